// Round 9
// baseline (162.209 us; speedup 1.0000x reference)
//
#include <hip/hip_runtime.h>

// out = x + softmax((x@Wq) @ (rs@Wk)^T) @ (rs@Wv)
// B=4 T=8 N=2048 C=D=128 M=2048. fp32 in/out, fp16 MFMA compute (f32 accum).
// R8: 64 q-rows/wave (halves K/V DS reads per q-row). 8-wave blocks =
//     4 q-groups(64q) x 2 kv-groups(32kv of each 64-tile); 256 q-rows/block;
//     grid 256 = 1 block/CU, XCD-paired batches. In-block kv merge (R7).

#define Bn 4
#define Tn 8
#define Nn 2048
#define Cn 128
#define Mn 2048
#define KVB 64
#define NT 32            // Mn/KVB
#define QROWS 256
#define NQT (Nn / QROWS) // 8

typedef __attribute__((ext_vector_type(4))) float f32x4;
typedef __attribute__((ext_vector_type(8))) _Float16 f16x8;
typedef __attribute__((address_space(3))) unsigned char lds_uc;
typedef const __attribute__((address_space(1))) unsigned char glb_uc;

__device__ __forceinline__ unsigned short f2h(float f) {
  _Float16 h = (_Float16)f;
  return __builtin_bit_cast(unsigned short, h);
}
__device__ __forceinline__ unsigned int pk2(float a, float b) {
  auto v = __builtin_amdgcn_cvt_pkrtz(a, b);
  return __builtin_bit_cast(unsigned int, v);
}
// 16B LDS read, 256B rows, swizzle (row&7)<<4
__device__ __forceinline__ f16x8 lds_read8(const unsigned char* base, int row,
                                           int colByte) {
  int byte = row * 256 + (colByte ^ ((row & 7) << 4));
  return *(const f16x8*)(base + byte);
}
// 16B LDS read, 128B rows, swizzle (row&7)<<4
__device__ __forceinline__ f16x8 lds_read8n(const unsigned char* base, int row,
                                            int colByte) {
  int byte = row * 128 + (colByte ^ ((row & 7) << 4));
  return *(const f16x8*)(base + byte);
}
__device__ __forceinline__ void gld16(const void* g, void* l) {
  __builtin_amdgcn_global_load_lds((glb_uc*)g, (lds_uc*)l, 16, 0, 0);
}

// ---------------------------------------------------------------------------
// Kernel A: per (b,kt): K tile [64 m][128 d] f16, 256B rows, swz (m&7)<<4;
// V^T tile [128 d][64 m] f16, 128B rows, swz (d&7)<<4. Tiles 16KB each.
// grid: B*32 = 128 blocks, 256 threads.
// ---------------------------------------------------------------------------
__global__ __launch_bounds__(256) void proj_kv_kernel(
    const float* __restrict__ rs, const float* __restrict__ Wk,
    const float* __restrict__ Wv, unsigned short* __restrict__ k_ws,
    unsigned short* __restrict__ vt_ws) {
  __shared__ unsigned char smem[48 * 1024];
  unsigned char* rsh = smem;             // [64][128] f16 swz (16KB)
  unsigned char* wt = smem + 16 * 1024;  // [128][128] f16 swz, W^T (32KB)

  const int bid = blockIdx.x;
  const int b = bid >> 5;
  const int kt = bid & 31;
  const int m0 = kt << 6;
  const int tid = threadIdx.x;
  const int wv = tid >> 6, lane = tid & 63;

  {
    const float4* g = (const float4*)(rs + ((size_t)b * Mn + m0) * Cn);
#pragma unroll
    for (int i = 0; i < 8; ++i) {
      int f = tid + i * 256;
      int row = f >> 5, c4 = f & 31;
      float4 v = g[f];
      int byte = row * 256 + ((c4 * 8) ^ ((row & 7) << 4));
      *(ushort4*)(rsh + byte) =
          make_ushort4(f2h(v.x), f2h(v.y), f2h(v.z), f2h(v.w));
    }
  }

#define STAGE_WT(Wp)                                                          \
  {                                                                           \
    const float4* g = (const float4*)(Wp);                                    \
    _Pragma("unroll") for (int i = 0; i < 16; ++i) {                          \
      int f = tid + i * 256;                                                  \
      int cc = f >> 5, d0 = (f & 31) * 4;                                     \
      float4 v = g[f];                                                        \
      float vv[4] = {v.x, v.y, v.z, v.w};                                     \
      _Pragma("unroll") for (int j = 0; j < 4; ++j) {                         \
        int row = d0 + j;                                                     \
        int byte = row * 256 + ((cc * 2) ^ ((row & 7) << 4));                 \
        *(unsigned short*)(wt + byte) = f2h(vv[j]);                           \
      }                                                                       \
    }                                                                         \
  }

  STAGE_WT(Wk);
  __syncthreads();

  const int arow = wv * 16 + (lane & 15);
  f16x8 ah[4];
#pragma unroll
  for (int ks = 0; ks < 4; ++ks)
    ah[ks] = lds_read8(rsh, arow, (lane >> 4) * 16 + ks * 64);

  f32x4 acc[8];
#pragma unroll
  for (int df = 0; df < 8; ++df) acc[df] = (f32x4)(0.0f);
#pragma unroll
  for (int ks = 0; ks < 4; ++ks)
#pragma unroll
    for (int df = 0; df < 8; ++df) {
      f16x8 bf = lds_read8(wt, df * 16 + (lane & 15), (lane >> 4) * 16 + ks * 64);
      acc[df] = __builtin_amdgcn_mfma_f32_16x16x32_f16(ah[ks], bf, acc[df], 0, 0, 0);
    }
  {
    unsigned char* kb = (unsigned char*)k_ws + ((size_t)b * NT + kt) * 16384;
#pragma unroll
    for (int df = 0; df < 8; ++df)
#pragma unroll
      for (int r = 0; r < 4; ++r) {
        int row = wv * 16 + (lane >> 4) * 4 + r;   // tile-local m 0..63
        int dcol = df * 16 + (lane & 15);
        int byte = row * 256 + ((dcol * 2) ^ ((row & 7) << 4));
        *(unsigned short*)(kb + byte) = f2h(acc[df][r]);
      }
  }
  __syncthreads();

  STAGE_WT(Wv);
  __syncthreads();
#pragma unroll
  for (int df = 0; df < 8; ++df) acc[df] = (f32x4)(0.0f);
#pragma unroll
  for (int ks = 0; ks < 4; ++ks)
#pragma unroll
    for (int df = 0; df < 8; ++df) {
      f16x8 bf = lds_read8(wt, df * 16 + (lane & 15), (lane >> 4) * 16 + ks * 64);
      acc[df] = __builtin_amdgcn_mfma_f32_16x16x32_f16(ah[ks], bf, acc[df], 0, 0, 0);
    }
  {
    unsigned char* vb = (unsigned char*)vt_ws + ((size_t)b * NT + kt) * 16384;
#pragma unroll
    for (int df = 0; df < 8; ++df)
#pragma unroll
      for (int r = 0; r < 4; ++r) {
        int row = wv * 16 + (lane >> 4) * 4 + r;   // tile-local m
        int dcol = df * 16 + (lane & 15);          // d (row of V^T tile)
        int byte = dcol * 128 + (((row * 2)) ^ ((dcol & 7) << 4));
        *(unsigned short*)(vb + byte) = f2h(acc[df][r]);
      }
  }
#undef STAGE_WT
}

// ---------------------------------------------------------------------------
// Kernel B: flash attention. grid 256 blocks x 512 thr (8 waves), 1 block/CU.
// wave = qg (wv&3: 64 q-rows) x kvg (wv>>2: 32-kv half of each 64 tile).
// LDS 128KB: prologue {x/q [256][128] @0 64K, wq^T @64K 32K};
//  main {K[2] @0 16K ea, V[2] @32K 16K ea, P @64K + wv*8K};
//  epilogue {partial O f16 @0 64K, ML @64K}.
// ---------------------------------------------------------------------------
__global__ __launch_bounds__(512, 2) void attn_kernel(
    const float* __restrict__ x, const float* __restrict__ Wq,
    const unsigned short* __restrict__ k_ws,
    const unsigned short* __restrict__ vt_ws, float* __restrict__ out) {
  __shared__ unsigned char smem[128 * 1024];

  const int bx = blockIdx.x;
  const int b = (bx & 7) >> 1;                    // batch per XCD pair
  const int idx = ((bx & 1) << 5) | (bx >> 3);    // 0..63
  const int t_ = idx >> 3;
  const int n0 = (idx & 7) * QROWS;
  const int tid = threadIdx.x;
  const int wv = tid >> 6, lane = tid & 63;
  const int qg = wv & 3, kvg = wv >> 2;
  const int c = lane & 15, g = lane >> 4;

  const float* xg = x + (((size_t)b * Tn + t_) * Nn + n0) * Cn;  // 256x128
  unsigned char* wqb = smem + 64 * 1024;
  unsigned char* pbw = smem + 64 * 1024 + wv * 8192;  // main loop P

  // ---- prologue: q = x@Wq (Wq pre-scaled by log2e) ----
  const float LOG2E = 1.4426950408889634f;
  {
    const float4* gp = (const float4*)xg;
#pragma unroll
    for (int ii = 0; ii < 16; ++ii) {
      int f = tid + ii * 512;
      int row = f >> 5, c4 = f & 31;
      float4 v = gp[f];
      int byte = row * 256 + ((c4 * 8) ^ ((row & 7) << 4));
      *(ushort4*)(smem + byte) =
          make_ushort4(f2h(v.x), f2h(v.y), f2h(v.z), f2h(v.w));
    }
  }
  {
    const float4* gp = (const float4*)Wq;
#pragma unroll
    for (int ii = 0; ii < 8; ++ii) {
      int f = tid + ii * 512;
      int cc = f >> 5, d0 = (f & 31) * 4;
      float4 v = gp[f];
      float vv[4] = {v.x, v.y, v.z, v.w};
#pragma unroll
      for (int j = 0; j < 4; ++j) {
        int row = d0 + j;
        int byte = row * 256 + ((cc * 2) ^ ((row & 7) << 4));
        *(unsigned short*)(wqb + byte) = f2h(vv[j] * LOG2E);
      }
    }
  }
  __syncthreads();

  {  // each wave projects its own 32 rows (wv*32..wv*32+31)
    f32x4 qacc[2][8];
#pragma unroll
    for (int rb = 0; rb < 2; ++rb)
#pragma unroll
      for (int df = 0; df < 8; ++df) qacc[rb][df] = (f32x4)(0.0f);
    f16x8 xf[2][4];
#pragma unroll
    for (int rb = 0; rb < 2; ++rb)
#pragma unroll
      for (int ks = 0; ks < 4; ++ks)
        xf[rb][ks] = lds_read8(smem, wv * 32 + rb * 16 + c, g * 16 + ks * 64);
#pragma unroll
    for (int ks = 0; ks < 4; ++ks)
#pragma unroll
      for (int df = 0; df < 8; ++df) {
        f16x8 bf = lds_read8(wqb, df * 16 + c, g * 16 + ks * 64);
        qacc[0][df] = __builtin_amdgcn_mfma_f32_16x16x32_f16(xf[0][ks], bf, qacc[0][df], 0, 0, 0);
        qacc[1][df] = __builtin_amdgcn_mfma_f32_16x16x32_f16(xf[1][ks], bf, qacc[1][df], 0, 0, 0);
      }
    // write q (f16) over the x area (own rows; in-wave write-after-read ok)
#pragma unroll
    for (int rb = 0; rb < 2; ++rb)
#pragma unroll
      for (int df = 0; df < 8; ++df)
#pragma unroll
        for (int r = 0; r < 4; ++r) {
          int row = wv * 32 + rb * 16 + g * 4 + r;
          int dq = df * 16 + c;
          int byte = row * 256 + ((dq * 2) ^ ((row & 7) << 4));
          *(unsigned short*)(smem + byte) = f2h(qacc[rb][df][r]);
        }
  }
  __syncthreads();
  // read this wave's 64 q-rows as B-fragments
  f16x8 qf[4][4];
#pragma unroll
  for (int qb = 0; qb < 4; ++qb)
#pragma unroll
    for (int ks = 0; ks < 4; ++ks)
      qf[qb][ks] = lds_read8(smem, qg * 64 + qb * 16 + c, g * 16 + ks * 64);
  __syncthreads();  // before staging overwrites @0

  // ---- main flash loop ----
  f32x4 o[4][8];
#pragma unroll
  for (int qb = 0; qb < 4; ++qb)
#pragma unroll
    for (int df = 0; df < 8; ++df) o[qb][df] = (f32x4)(0.0f);
  float mrow[4] = {-INFINITY, -INFINITY, -INFINITY, -INFINITY};
  float lrow[4] = {0.f, 0.f, 0.f, 0.f};

  const unsigned char* khg = (const unsigned char*)k_ws + (size_t)b * NT * 16384;
  const unsigned char* vtg = (const unsigned char*)vt_ws + (size_t)b * NT * 16384;

  auto stage = [&](int t) {
    unsigned char* kd = smem + (t & 1) * 16384 + tid * 16;
    unsigned char* vd = smem + 32 * 1024 + (t & 1) * 16384 + tid * 16;
    const unsigned char* ks_ = khg + (size_t)t * 16384 + tid * 16;
    const unsigned char* vs = vtg + (size_t)t * 16384 + tid * 16;
    gld16(ks_, kd);
    gld16(ks_ + 8192, kd + 8192);
    gld16(vs, vd);
    gld16(vs + 8192, vd + 8192);
  };

  stage(0);
  __syncthreads();

#pragma unroll 1
  for (int t = 0; t < NT; ++t) {
    unsigned char* kb = smem + (t & 1) * 16384;
    unsigned char* vb = smem + 32 * 1024 + (t & 1) * 16384;
    if (t + 1 < NT) stage(t + 1);

    // QK^T: S^T[32 kv-half][64 q]
    f32x4 st[4][2];
#pragma unroll
    for (int qb = 0; qb < 4; ++qb)
#pragma unroll
      for (int kvb = 0; kvb < 2; ++kvb) st[qb][kvb] = (f32x4)(0.0f);
    __builtin_amdgcn_s_setprio(1);
#pragma unroll
    for (int ks = 0; ks < 4; ++ks)
#pragma unroll
      for (int kvb = 0; kvb < 2; ++kvb) {
        f16x8 kf = lds_read8(kb, kvg * 32 + kvb * 16 + c, g * 16 + ks * 64);
#pragma unroll
        for (int qb = 0; qb < 4; ++qb)
          st[qb][kvb] = __builtin_amdgcn_mfma_f32_16x16x32_f16(kf, qf[qb][ks], st[qb][kvb], 0, 0, 0);
      }
    __builtin_amdgcn_s_setprio(0);

    // online softmax (log2 units), vote-only defer-max, pack P
#pragma unroll
    for (int qb = 0; qb < 4; ++qb) {
      float tm = fmaxf(fmaxf(fmaxf(st[qb][0][0], st[qb][0][1]),
                             fmaxf(st[qb][0][2], st[qb][0][3])),
                       fmaxf(fmaxf(st[qb][1][0], st[qb][1][1]),
                             fmaxf(st[qb][1][2], st[qb][1][3])));
      if (__any(tm > mrow[qb] + 8.f)) {  // rare path
        tm = fmaxf(tm, __shfl_xor(tm, 16));
        tm = fmaxf(tm, __shfl_xor(tm, 32));
        float newm = fmaxf(mrow[qb], tm);
        float scl = exp2f(mrow[qb] - newm);
#pragma unroll
        for (int df = 0; df < 8; ++df) o[qb][df] *= scl;
        lrow[qb] *= scl;
        mrow[qb] = newm;
      }
      float mn = mrow[qb];
      float ps = 0.f;
      int prow = qb * 16 + c;
      int pswz = (prow & 7) << 4;
#pragma unroll
      for (int kvb = 0; kvb < 2; ++kvb) {
        float p0 = exp2f(st[qb][kvb][0] - mn);
        float p1 = exp2f(st[qb][kvb][1] - mn);
        float p2 = exp2f(st[qb][kvb][2] - mn);
        float p3 = exp2f(st[qb][kvb][3] - mn);
        ps += (p0 + p1) + (p2 + p3);
        int kv2 = kvb * 32 + g * 8;  // kv-local * 2 bytes
        *(unsigned int*)(pbw + prow * 128 + ((kv2) ^ pswz)) = pk2(p0, p1);
        *(unsigned int*)(pbw + prow * 128 + ((kv2 + 4) ^ pswz)) = pk2(p2, p3);
      }
      lrow[qb] += ps;
    }

    // P B-fragments (in-wave write->read)
    f16x8 pa[4];
#pragma unroll
    for (int qb = 0; qb < 4; ++qb)
      pa[qb] = lds_read8n(pbw, qb * 16 + c, g * 16);

    // PV: O^T[128 d][64 q] += V^T(kv-half) @ P  (K=32 contraction)
    __builtin_amdgcn_s_setprio(1);
#pragma unroll
    for (int df = 0; df < 8; ++df) {
      f16x8 vf = lds_read8n(vb, df * 16 + c, kvg * 64 + g * 16);
#pragma unroll
      for (int qb = 0; qb < 4; ++qb)
        o[qb][df] = __builtin_amdgcn_mfma_f32_16x16x32_f16(vf, pa[qb], o[qb][df], 0, 0, 0);
    }
    __builtin_amdgcn_s_setprio(0);
    __syncthreads();
  }

  // ---- epilogue: merge kv-halves, out = x + O/l ----
#pragma unroll
  for (int qb = 0; qb < 4; ++qb) {
    lrow[qb] += __shfl_xor(lrow[qb], 16);
    lrow[qb] += __shfl_xor(lrow[qb], 32);
  }
  float* ML = (float*)(smem + 64 * 1024);  // [8 wv][4 qb][16 c][2]
  if (g == 0) {
#pragma unroll
    for (int qb = 0; qb < 4; ++qb) {
      ML[((wv * 4 + qb) * 16 + c) * 2 + 0] = mrow[qb];
      ML[((wv * 4 + qb) * 16 + c) * 2 + 1] = lrow[qb];
    }
  }
  __syncthreads();
  const int pw = wv ^ 4;
  float coef[4];
#pragma unroll
  for (int qb = 0; qb < 4; ++qb) {
    float mp = ML[((pw * 4 + qb) * 16 + c) * 2 + 0];
    float lp = ML[((pw * 4 + qb) * 16 + c) * 2 + 1];
    float m12 = fmaxf(mrow[qb], mp);
    float s0 = exp2f(mrow[qb] - m12);
    float sp = exp2f(mp - m12);
    float ltot = lrow[qb] * s0 + lp * sp;
    coef[qb] = s0 / ltot;
  }
  __syncthreads();
  if (kvg == 1) {  // write own O*coef (f16) to @0: [256 q][128 d] swz
#pragma unroll
    for (int qb = 0; qb < 4; ++qb)
#pragma unroll
      for (int df = 0; df < 8; ++df)
#pragma unroll
        for (int h = 0; h < 2; ++h) {
          int row = qg * 64 + qb * 16 + c;
          int d0 = df * 16 + g * 4 + 2 * h;
          int byte = row * 256 + ((d0 * 2) ^ ((row & 7) << 4));
          *(unsigned int*)(smem + byte) =
              pk2(o[qb][df][2 * h] * coef[qb], o[qb][df][2 * h + 1] * coef[qb]);
        }
  }
  __syncthreads();
  if (kvg == 0) {  // merge + residual + global store (16B per (qb,df))
    float* og = out + (((size_t)b * Tn + t_) * Nn + n0) * Cn;
#pragma unroll
    for (int qb = 0; qb < 4; ++qb)
#pragma unroll
      for (int df = 0; df < 8; ++df) {
        int row = qg * 64 + qb * 16 + c;
        int d0 = df * 16 + g * 4;
        int byte = row * 256 + ((d0 * 2) ^ ((row & 7) << 4));
        unsigned int v0 = *(const unsigned int*)(smem + byte);
        unsigned int v1 = *(const unsigned int*)(smem + byte + 4);
        float4 xv = *(const float4*)(xg + (size_t)row * Cn + d0);
        float4 r;
        r.x = o[qb][df][0] * coef[qb] +
              (float)__builtin_bit_cast(_Float16, (unsigned short)(v0 & 0xffffu)) + xv.x;
        r.y = o[qb][df][1] * coef[qb] +
              (float)__builtin_bit_cast(_Float16, (unsigned short)(v0 >> 16)) + xv.y;
        r.z = o[qb][df][2] * coef[qb] +
              (float)__builtin_bit_cast(_Float16, (unsigned short)(v1 & 0xffffu)) + xv.z;
        r.w = o[qb][df][3] * coef[qb] +
              (float)__builtin_bit_cast(_Float16, (unsigned short)(v1 >> 16)) + xv.w;
        *(float4*)(og + (size_t)row * Cn + d0) = r;
      }
  }
}

extern "C" void kernel_launch(void* const* d_in, const int* in_sizes, int n_in,
                              void* d_out, int out_size, void* d_ws,
                              size_t ws_size, hipStream_t stream) {
  const float* x = (const float*)d_in[0];
  const float* rs = (const float*)d_in[1];
  const float* Wq = (const float*)d_in[2];
  const float* Wk = (const float*)d_in[3];
  const float* Wv = (const float*)d_in[4];
  float* out = (float*)d_out;

  // ws: K f16 tiles [B][32][16KB] (2MB) | V^T tiles [B][32][16KB] (2MB)
  unsigned short* k_ws = (unsigned short*)d_ws;
  unsigned short* vt_ws = k_ws + (size_t)Bn * Mn * Cn;

  proj_kv_kernel<<<Bn * NT, 256, 0, stream>>>(rs, Wk, Wv, k_ws, vt_ws);
  attn_kernel<<<Bn * Tn * NQT, 512, 0, stream>>>(x, Wq, k_ws, vt_ws, out);
}

// Round 10
// 127.293 us; speedup vs baseline: 1.2743x; 1.2743x over previous
//
#include <hip/hip_runtime.h>

// out = x + softmax((x@Wq) @ (rs@Wk)^T) @ (rs@Wv)
// B=4 T=8 N=2048 C=D=128 M=2048. fp32 in/out, fp16 MFMA compute (f32 accum).
// R9 = R4 (best, 122us) + 4-bit LDS swizzles (reads spread over 16 slots
//      instead of 8 -> kill the 1.35e7 bank-conflict cycles) + proven softmax
//      micro-opts (exp2/LOG2E, vote-only defer-max, per-lane partial l).

#define Bn 4
#define Tn 8
#define Nn 2048
#define Cn 128
#define Mn 2048
#define NTILES 32        // Mn/64
#define QROWS 128
#define NQT (Nn / QROWS) // 16

typedef __attribute__((ext_vector_type(4))) float f32x4;
typedef __attribute__((ext_vector_type(8))) _Float16 f16x8;
typedef __attribute__((address_space(3))) unsigned char lds_uc;
typedef const __attribute__((address_space(1))) unsigned char glb_uc;

__device__ __forceinline__ unsigned short f2h(float f) {
  _Float16 h = (_Float16)f;
  return __builtin_bit_cast(unsigned short, h);
}
__device__ __forceinline__ unsigned int pk2(float a, float b) {
  auto v = __builtin_amdgcn_cvt_pkrtz(a, b);
  return __builtin_bit_cast(unsigned int, v);
}
// 16B LDS read, 256B rows, 4-bit swizzle (row&15)<<4 (16-slot spread)
__device__ __forceinline__ f16x8 lds_read8w(const unsigned char* base, int row,
                                            int colByte) {
  int byte = row * 256 + (colByte ^ ((row & 15) << 4));
  return *(const f16x8*)(base + byte);
}
__device__ __forceinline__ void gld16(const void* g, void* l) {
  __builtin_amdgcn_global_load_lds((glb_uc*)g, (lds_uc*)l, 16, 0, 0);
}

// ---------------------------------------------------------------------------
// Kernel A: per (b,kt): K tile [64 m][128 d] f16, 256B rows, swz (m&15)<<4;
// V^T tile super-row packed: srow=d>>1 (64 rows x 256B), col=(d&1)*128+m*2,
// swz (srow&15)<<4. Tiles 16KB each, contiguous.
// grid: B*32 = 128 blocks, 256 threads. LDS 48KB.
// ---------------------------------------------------------------------------
__global__ __launch_bounds__(256) void proj_kv_kernel(
    const float* __restrict__ rs, const float* __restrict__ Wk,
    const float* __restrict__ Wv, unsigned short* __restrict__ k_ws,
    unsigned short* __restrict__ vt_ws) {
  __shared__ unsigned char smem[48 * 1024];
  unsigned char* rsh = smem;             // [64][128] f16 swz (16KB)
  unsigned char* wt = smem + 16 * 1024;  // [128][128] f16 swz, W^T (32KB)

  const int bid = blockIdx.x;
  const int b = bid >> 5;
  const int kt = bid & 31;
  const int m0 = kt << 6;
  const int tid = threadIdx.x;
  const int wv = tid >> 6, lane = tid & 63;

  {
    const float4* g = (const float4*)(rs + ((size_t)b * Mn + m0) * Cn);
#pragma unroll
    for (int i = 0; i < 8; ++i) {
      int f = tid + i * 256;
      int row = f >> 5, c4 = f & 31;
      float4 v = g[f];
      int byte = row * 256 + ((c4 * 8) ^ ((row & 15) << 4));
      *(ushort4*)(rsh + byte) =
          make_ushort4(f2h(v.x), f2h(v.y), f2h(v.z), f2h(v.w));
    }
  }

#define STAGE_WT(Wp)                                                          \
  {                                                                           \
    const float4* g = (const float4*)(Wp);                                    \
    _Pragma("unroll") for (int i = 0; i < 16; ++i) {                          \
      int f = tid + i * 256;                                                  \
      int cc = f >> 5, d0 = (f & 31) * 4;                                     \
      float4 v = g[f];                                                        \
      float vv[4] = {v.x, v.y, v.z, v.w};                                     \
      _Pragma("unroll") for (int j = 0; j < 4; ++j) {                         \
        int row = d0 + j;                                                     \
        int byte = row * 256 + ((cc * 2) ^ ((row & 15) << 4));                \
        *(unsigned short*)(wt + byte) = f2h(vv[j]);                           \
      }                                                                       \
    }                                                                         \
  }

  STAGE_WT(Wk);
  __syncthreads();

  const int arow = wv * 16 + (lane & 15);
  f16x8 ah[4];
#pragma unroll
  for (int ks = 0; ks < 4; ++ks)
    ah[ks] = lds_read8w(rsh, arow, (lane >> 4) * 16 + ks * 64);

  f32x4 acc[8];
#pragma unroll
  for (int df = 0; df < 8; ++df) acc[df] = (f32x4)(0.0f);
#pragma unroll
  for (int ks = 0; ks < 4; ++ks)
#pragma unroll
    for (int df = 0; df < 8; ++df) {
      f16x8 bf = lds_read8w(wt, df * 16 + (lane & 15), (lane >> 4) * 16 + ks * 64);
      acc[df] = __builtin_amdgcn_mfma_f32_16x16x32_f16(ah[ks], bf, acc[df], 0, 0, 0);
    }
  {
    unsigned char* kb = (unsigned char*)k_ws + ((size_t)b * NTILES + kt) * 16384;
#pragma unroll
    for (int df = 0; df < 8; ++df)
#pragma unroll
      for (int r = 0; r < 4; ++r) {
        int row = wv * 16 + (lane >> 4) * 4 + r;   // tile-local m 0..63
        int dcol = df * 16 + (lane & 15);
        int byte = row * 256 + ((dcol * 2) ^ ((row & 15) << 4));
        *(unsigned short*)(kb + byte) = f2h(acc[df][r]);
      }
  }
  __syncthreads();

  STAGE_WT(Wv);
  __syncthreads();
#pragma unroll
  for (int df = 0; df < 8; ++df) acc[df] = (f32x4)(0.0f);
#pragma unroll
  for (int ks = 0; ks < 4; ++ks)
#pragma unroll
    for (int df = 0; df < 8; ++df) {
      f16x8 bf = lds_read8w(wt, df * 16 + (lane & 15), (lane >> 4) * 16 + ks * 64);
      acc[df] = __builtin_amdgcn_mfma_f32_16x16x32_f16(ah[ks], bf, acc[df], 0, 0, 0);
    }
  {
    unsigned char* vb = (unsigned char*)vt_ws + ((size_t)b * NTILES + kt) * 16384;
#pragma unroll
    for (int df = 0; df < 8; ++df)
#pragma unroll
      for (int r = 0; r < 4; ++r) {
        int row = wv * 16 + (lane >> 4) * 4 + r;   // tile-local m
        int dcol = df * 16 + (lane & 15);          // d
        int srow = dcol >> 1;
        int byte = srow * 256 +
                   ((((dcol & 1) << 7) | (row * 2)) ^ ((srow & 15) << 4));
        *(unsigned short*)(vb + byte) = f2h(acc[df][r]);
      }
  }
#undef STAGE_WT
}

// ---------------------------------------------------------------------------
// Kernel B: fused flash attention, transposed dataflow (R4 structure).
// grid 512 blocks x 256 thr (4 waves x 32 q-rows). LDS 80KB:
//  prologue: xa[128][128]f16 @0 (32K), wq^T @32K (32K)
//  main: B0 @0 {K 16K | Vt 16K}, B1 @32K, P @64K + wv*4K ([16 q][256B])
//  epilogue: O^T f32 bounce @0 (64K)
// ---------------------------------------------------------------------------
__global__ __launch_bounds__(256, 2) void attn_kernel(
    const float* __restrict__ x, const float* __restrict__ Wq,
    const unsigned short* __restrict__ k_ws,
    const unsigned short* __restrict__ vt_ws, float* __restrict__ out) {
  __shared__ unsigned char smem[80 * 1024];

  const int bx = blockIdx.x;
  const int wb = ((bx & 7) << 6) | (bx >> 3);  // XCD swizzle (512 % 8 == 0)
  const int b = wb >> 7;
  const int t_ = (wb >> 4) & 7;
  const int n0 = (wb & 15) * QROWS;
  const int tid = threadIdx.x;
  const int wv = tid >> 6, lane = tid & 63;
  const int c = lane & 15, g = lane >> 4;

  const float* xg = x + (((size_t)b * Tn + t_) * Nn + n0) * Cn;  // 128x128
  unsigned char* xa = smem;
  unsigned char* wqb = smem + 32 * 1024;
  unsigned char* pb = smem + 64 * 1024 + wv * 4096;  // per-wave P [16 q][256B]

  // ---- prologue: q = x@Wq (f16) * log2e, kept as B-fragments in regs ----
  const float LOG2E = 1.4426950408889634f;
  {
    const float4* gp = (const float4*)xg;
#pragma unroll
    for (int ii = 0; ii < 16; ++ii) {
      int f = tid + ii * 256;
      int row = f >> 5, c4 = f & 31;
      float4 v = gp[f];
      int byte = row * 256 + ((c4 * 8) ^ ((row & 15) << 4));
      *(ushort4*)(xa + byte) =
          make_ushort4(f2h(v.x), f2h(v.y), f2h(v.z), f2h(v.w));
    }
  }
  {
    const float4* gp = (const float4*)Wq;
#pragma unroll
    for (int ii = 0; ii < 16; ++ii) {
      int f = tid + ii * 256;
      int cc = f >> 5, d0 = (f & 31) * 4;
      float4 v = gp[f];
      float vv[4] = {v.x, v.y, v.z, v.w};
#pragma unroll
      for (int j = 0; j < 4; ++j) {
        int row = d0 + j;
        int byte = row * 256 + ((cc * 2) ^ ((row & 15) << 4));
        *(unsigned short*)(wqb + byte) = f2h(vv[j] * LOG2E);
      }
    }
  }
  __syncthreads();

  f32x4 qacc[2][8];
#pragma unroll
  for (int rb = 0; rb < 2; ++rb)
#pragma unroll
    for (int df = 0; df < 8; ++df) qacc[rb][df] = (f32x4)(0.0f);
  {
    f16x8 xf[2][4];
#pragma unroll
    for (int rb = 0; rb < 2; ++rb)
#pragma unroll
      for (int ks = 0; ks < 4; ++ks)
        xf[rb][ks] = lds_read8w(xa, wv * 32 + rb * 16 + c, g * 16 + ks * 64);
#pragma unroll
    for (int ks = 0; ks < 4; ++ks)
#pragma unroll
      for (int df = 0; df < 8; ++df) {
        f16x8 bf = lds_read8w(wqb, df * 16 + c, g * 16 + ks * 64);
        qacc[0][df] = __builtin_amdgcn_mfma_f32_16x16x32_f16(xf[0][ks], bf, qacc[0][df], 0, 0, 0);
        qacc[1][df] = __builtin_amdgcn_mfma_f32_16x16x32_f16(xf[1][ks], bf, qacc[1][df], 0, 0, 0);
      }
  }
  // write q (f16) into own rows of xa, re-read as fragments (wave-local)
#pragma unroll
  for (int rb = 0; rb < 2; ++rb)
#pragma unroll
    for (int df = 0; df < 8; ++df)
#pragma unroll
      for (int r = 0; r < 4; ++r) {
        int row = wv * 32 + rb * 16 + g * 4 + r;
        int col = df * 16 + c;
        int byte = row * 256 + ((col * 2) ^ ((row & 15) << 4));
        *(unsigned short*)(xa + byte) = f2h(qacc[rb][df][r]);
      }
  f16x8 qf[2][4];
#pragma unroll
  for (int rb = 0; rb < 2; ++rb)
#pragma unroll
    for (int ks = 0; ks < 4; ++ks)
      qf[rb][ks] = lds_read8w(xa, wv * 32 + rb * 16 + c, g * 16 + ks * 64);
  __syncthreads();  // all waves done with xa/wqb before K/V staging

  // ---- main flash loop ----
  f32x4 o[2][8];  // O^T fragments: col c = q-row, rows = d
#pragma unroll
  for (int rb = 0; rb < 2; ++rb)
#pragma unroll
    for (int df = 0; df < 8; ++df) o[rb][df] = (f32x4)(0.0f);
  float mrow[2] = {-INFINITY, -INFINITY};
  float lrow[2] = {0.f, 0.f};  // per-lane partial, reduced at end

  const unsigned char* khg = (const unsigned char*)k_ws + (size_t)b * NTILES * 16384;
  const unsigned char* vtg = (const unsigned char*)vt_ws + (size_t)b * NTILES * 16384;

  auto stage = [&](unsigned char* buf, int kt) {
    const unsigned char* kh = khg + (size_t)kt * 16384;
    const unsigned char* vt = vtg + (size_t)kt * 16384;
    int o16 = tid * 16;  // 256 thr x 16B = 4KB per call
#pragma unroll
    for (int h = 0; h < 4; ++h) {
      gld16(kh + o16 + h * 4096, buf + o16 + h * 4096);
      gld16(vt + o16 + h * 4096, buf + 16384 + o16 + h * 4096);
    }
  };

  auto do_tile = [&](unsigned char* buf) {
    unsigned char* kh = buf;
    unsigned char* vt = buf + 16384;
    // S^T[kv][q] = K @ Q : A=K rows(kv), B=Q cols(q)
    f32x4 st[2][4];
#pragma unroll
    for (int rb = 0; rb < 2; ++rb)
#pragma unroll
      for (int kvb = 0; kvb < 4; ++kvb) st[rb][kvb] = (f32x4)(0.0f);
    __builtin_amdgcn_s_setprio(1);
#pragma unroll
    for (int ks = 0; ks < 4; ++ks)
#pragma unroll
      for (int kvb = 0; kvb < 4; ++kvb) {
        f16x8 kf = lds_read8w(kh, kvb * 16 + c, g * 16 + ks * 64);
        st[0][kvb] = __builtin_amdgcn_mfma_f32_16x16x32_f16(kf, qf[0][ks], st[0][kvb], 0, 0, 0);
        st[1][kvb] = __builtin_amdgcn_mfma_f32_16x16x32_f16(kf, qf[1][ks], st[1][kvb], 0, 0, 0);
      }
    __builtin_amdgcn_s_setprio(0);

    // online softmax (log2 units): lane owns q-row c; vote-only defer-max
#pragma unroll
    for (int rb = 0; rb < 2; ++rb) {
      float tm = st[rb][0][0];
#pragma unroll
      for (int kvb = 0; kvb < 4; ++kvb)
#pragma unroll
        for (int r = 0; r < 4; ++r) tm = fmaxf(tm, st[rb][kvb][r]);
      if (__any(tm > mrow[rb] + 8.f)) {  // rare path
        tm = fmaxf(tm, __shfl_xor(tm, 16));
        tm = fmaxf(tm, __shfl_xor(tm, 32));
        float newm = fmaxf(mrow[rb], tm);
        float scl = exp2f(mrow[rb] - newm);
#pragma unroll
        for (int df = 0; df < 8; ++df) o[rb][df] *= scl;
        lrow[rb] *= scl;
        mrow[rb] = newm;
      }
      float mn = mrow[rb];
      float ps = 0.f;
      int swz = (c & 15) << 4;
#pragma unroll
      for (int kvb = 0; kvb < 4; ++kvb) {
        float p0 = exp2f(st[rb][kvb][0] - mn);
        float p1 = exp2f(st[rb][kvb][1] - mn);
        float p2 = exp2f(st[rb][kvb][2] - mn);
        float p3 = exp2f(st[rb][kvb][3] - mn);
        ps += (p0 + p1) + (p2 + p3);
        int kv2 = rb * 128 + kvb * 32 + g * 8;  // col byte within 256B row
        *(unsigned int*)(pb + c * 256 + (kv2 ^ swz)) = pk2(p0, p1);
        *(unsigned int*)(pb + c * 256 + ((kv2 + 4) ^ swz)) = pk2(p2, p3);
      }
      lrow[rb] += ps;
    }

    // P fragments (in-wave write->read): row c, col rb*128 + {g*16, g*16+64}
    f16x8 pa[2][2];
#pragma unroll
    for (int rb = 0; rb < 2; ++rb)
#pragma unroll
      for (int ks = 0; ks < 2; ++ks)
        pa[rb][ks] = lds_read8w(pb, c, rb * 128 + g * 16 + ks * 64);

    // O^T += V^T @ P : A=V^T rows(d, super-row packed), B=P cols(q)
    __builtin_amdgcn_s_setprio(1);
#pragma unroll
    for (int ks = 0; ks < 2; ++ks)
#pragma unroll
      for (int df = 0; df < 8; ++df) {
        int d = df * 16 + c;
        int srow = d >> 1;
        int byte = srow * 256 +
                   ((((d & 1) << 7) | (g * 16 + ks * 64)) ^ ((srow & 15) << 4));
        f16x8 vf = *(const f16x8*)(vt + byte);
        o[0][df] = __builtin_amdgcn_mfma_f32_16x16x32_f16(vf, pa[0][ks], o[0][df], 0, 0, 0);
        o[1][df] = __builtin_amdgcn_mfma_f32_16x16x32_f16(vf, pa[1][ks], o[1][df], 0, 0, 0);
      }
    __builtin_amdgcn_s_setprio(0);
  };

  unsigned char* B0 = smem;
  unsigned char* B1 = smem + 32 * 1024;
  stage(B0, 0);
  __syncthreads();
#pragma unroll 1
  for (int it = 0; it < 16; ++it) {
    int kt = it * 2;
    stage(B1, kt + 1);
    do_tile(B0);
    __syncthreads();
    if (kt + 2 < NTILES) stage(B0, kt + 2);
    do_tile(B1);
    __syncthreads();
  }

  // ---- epilogue: l-reduce, O^T f32 bounce, out = x + O/l ----
#pragma unroll
  for (int rb = 0; rb < 2; ++rb) {
    lrow[rb] += __shfl_xor(lrow[rb], 16);
    lrow[rb] += __shfl_xor(lrow[rb], 32);
  }
  float inv[2] = {1.0f / lrow[0], 1.0f / lrow[1]};
#pragma unroll
  for (int rb = 0; rb < 2; ++rb)
#pragma unroll
    for (int df = 0; df < 8; ++df)
#pragma unroll
      for (int r = 0; r < 4; ++r) {
        int row = wv * 32 + rb * 16 + c;     // q-row (block-local)
        int d = df * 16 + g * 4 + r;
        int byte = row * 512 + ((d * 4) ^ ((row & 7) << 4));
        *(float*)(smem + byte) = o[rb][df][r] * inv[rb];
      }
  __syncthreads();
  {
    const float4* xg4 = (const float4*)xg;
    float4* og4 = (float4*)(out + (((size_t)b * Tn + t_) * Nn + n0) * Cn);
#pragma unroll
    for (int ii = 0; ii < 16; ++ii) {
      int f = tid + ii * 256;
      int row = f >> 5, c4 = f & 31;
      int byte = row * 512 + ((c4 * 16) ^ ((row & 7) << 4));
      f32x4 v = *(const f32x4*)(smem + byte);
      float4 xv = xg4[f];
      og4[f] = make_float4(xv.x + v[0], xv.y + v[1], xv.z + v[2], xv.w + v[3]);
    }
  }
}

extern "C" void kernel_launch(void* const* d_in, const int* in_sizes, int n_in,
                              void* d_out, int out_size, void* d_ws,
                              size_t ws_size, hipStream_t stream) {
  const float* x = (const float*)d_in[0];
  const float* rs = (const float*)d_in[1];
  const float* Wq = (const float*)d_in[2];
  const float* Wk = (const float*)d_in[3];
  const float* Wv = (const float*)d_in[4];
  float* out = (float*)d_out;

  // ws: K f16 tiles [B][32][16KB] (2MB) | V^T tiles [B][32][16KB] (2MB)
  unsigned short* k_ws = (unsigned short*)d_ws;
  unsigned short* vt_ws = k_ws + (size_t)Bn * Mn * Cn;

  proj_kv_kernel<<<Bn * NTILES, 256, 0, stream>>>(rs, Wk, Wv, k_ws, vt_ws);
  attn_kernel<<<Bn * Tn * NQT, 256, 0, stream>>>(x, Wq, k_ws, vt_ws, out);
}

// Round 11
// 121.886 us; speedup vs baseline: 1.3308x; 1.0444x over previous
//
#include <hip/hip_runtime.h>

// out = x + softmax((x@Wq) @ (rs@Wk)^T) @ (rs@Wv)
// B=4 T=8 N=2048 C=D=128 M=2048. fp32 in/out, fp16 MFMA compute (f32 accum).
// R10: 32x32x16 MFMA, swapped operands; S/P fully in registers (lane owns one
//      q-row); P->B-frags via cvt_pkrtz + v_permlane32_swap (no P LDS);
//      softmax = reg tree + 1 shuffle. LDS 64K = K[2]+V[2] only.

#define Bn 4
#define Tn 8
#define Nn 2048
#define Cn 128
#define Mn 2048
#define NTILES 32        // Mn/64
#define QROWS 128
#define NQT (Nn / QROWS) // 16

typedef __attribute__((ext_vector_type(4))) float f32x4;
typedef __attribute__((ext_vector_type(16))) float f32x16;
typedef __attribute__((ext_vector_type(8))) _Float16 f16x8;
typedef __attribute__((ext_vector_type(4))) unsigned int u32x4;
typedef __attribute__((address_space(3))) unsigned char lds_uc;
typedef const __attribute__((address_space(1))) unsigned char glb_uc;

__device__ __forceinline__ unsigned short f2h(float f) {
  _Float16 h = (_Float16)f;
  return __builtin_bit_cast(unsigned short, h);
}
__device__ __forceinline__ unsigned int pk2(float a, float b) {
  auto v = __builtin_amdgcn_cvt_pkrtz(a, b);
  return __builtin_bit_cast(unsigned int, v);
}
// 16B LDS read, 256B rows, swizzle (row&15)<<4
__device__ __forceinline__ f16x8 lds_read8w(const unsigned char* base, int row,
                                            int colByte) {
  int byte = row * 256 + (colByte ^ ((row & 15) << 4));
  return *(const f16x8*)(base + byte);
}
// 16B LDS read, 128B rows, swizzle (row&7)<<4
__device__ __forceinline__ f16x8 lds_read8v(const unsigned char* base, int row,
                                            int colByte) {
  int byte = row * 128 + (colByte ^ ((row & 7) << 4));
  return *(const f16x8*)(base + byte);
}
__device__ __forceinline__ void gld16(const void* g, void* l) {
  __builtin_amdgcn_global_load_lds((glb_uc*)g, (lds_uc*)l, 16, 0, 0);
}

// Build one PV B-frag (16 kv rows) from 8 P values in s[base..base+7].
// VGPR0=r0 of swap(pk(p0,p1),pk(p4,p5)); VGPR2=r1; VGPR1/3 from (p2,p3,p6,p7).
#define MKPF(dst, sv, base)                                        \
  {                                                                \
    unsigned a0 = pk2(sv[base + 0], sv[base + 1]);                 \
    unsigned b0 = pk2(sv[base + 4], sv[base + 5]);                 \
    unsigned a1 = pk2(sv[base + 2], sv[base + 3]);                 \
    unsigned b1 = pk2(sv[base + 6], sv[base + 7]);                 \
    asm("v_permlane32_swap_b32 %0, %1" : "+v"(a0), "+v"(b0));      \
    asm("v_permlane32_swap_b32 %0, %1" : "+v"(a1), "+v"(b1));      \
    u32x4 tmp = {a0, a1, b0, b1};                                  \
    dst = __builtin_bit_cast(f16x8, tmp);                          \
  }

// ---------------------------------------------------------------------------
// Kernel A: per (b,kt): K tile [64 kv][128 d] f16, 256B rows, swz (kv&15)<<4;
// V^T tile [128 d][64 m] f16, 128B rows, swz (d&7)<<4. Tiles 16KB each.
// grid: B*32 = 128 blocks, 256 threads. LDS 48KB.
// ---------------------------------------------------------------------------
__global__ __launch_bounds__(256) void proj_kv_kernel(
    const float* __restrict__ rs, const float* __restrict__ Wk,
    const float* __restrict__ Wv, unsigned short* __restrict__ k_ws,
    unsigned short* __restrict__ vt_ws) {
  __shared__ unsigned char smem[48 * 1024];
  unsigned char* rsh = smem;             // [64][128] f16 swz (16KB)
  unsigned char* wt = smem + 16 * 1024;  // [128][128] f16 swz, W^T (32KB)

  const int bid = blockIdx.x;
  const int b = bid >> 5;
  const int kt = bid & 31;
  const int m0 = kt << 6;
  const int tid = threadIdx.x;
  const int wv = tid >> 6, lane = tid & 63;

  {
    const float4* g = (const float4*)(rs + ((size_t)b * Mn + m0) * Cn);
#pragma unroll
    for (int i = 0; i < 8; ++i) {
      int f = tid + i * 256;
      int row = f >> 5, c4 = f & 31;
      float4 v = g[f];
      int byte = row * 256 + ((c4 * 8) ^ ((row & 15) << 4));
      *(ushort4*)(rsh + byte) =
          make_ushort4(f2h(v.x), f2h(v.y), f2h(v.z), f2h(v.w));
    }
  }

#define STAGE_WT(Wp)                                                          \
  {                                                                           \
    const float4* g = (const float4*)(Wp);                                    \
    _Pragma("unroll") for (int i = 0; i < 16; ++i) {                          \
      int f = tid + i * 256;                                                  \
      int cc = f >> 5, d0 = (f & 31) * 4;                                     \
      float4 v = g[f];                                                        \
      float vv[4] = {v.x, v.y, v.z, v.w};                                     \
      _Pragma("unroll") for (int j = 0; j < 4; ++j) {                         \
        int row = d0 + j;                                                     \
        int byte = row * 256 + ((cc * 2) ^ ((row & 15) << 4));                \
        *(unsigned short*)(wt + byte) = f2h(vv[j]);                           \
      }                                                                       \
    }                                                                         \
  }

  STAGE_WT(Wk);
  __syncthreads();

  const int arow = wv * 16 + (lane & 15);
  f16x8 ah[4];
#pragma unroll
  for (int ks = 0; ks < 4; ++ks)
    ah[ks] = lds_read8w(rsh, arow, (lane >> 4) * 16 + ks * 64);

  f32x4 acc[8];
#pragma unroll
  for (int df = 0; df < 8; ++df) acc[df] = (f32x4)(0.0f);
#pragma unroll
  for (int ks = 0; ks < 4; ++ks)
#pragma unroll
    for (int df = 0; df < 8; ++df) {
      f16x8 bf = lds_read8w(wt, df * 16 + (lane & 15), (lane >> 4) * 16 + ks * 64);
      acc[df] = __builtin_amdgcn_mfma_f32_16x16x32_f16(ah[ks], bf, acc[df], 0, 0, 0);
    }
  {
    unsigned char* kb = (unsigned char*)k_ws + ((size_t)b * NTILES + kt) * 16384;
#pragma unroll
    for (int df = 0; df < 8; ++df)
#pragma unroll
      for (int r = 0; r < 4; ++r) {
        int row = wv * 16 + (lane >> 4) * 4 + r;   // tile-local kv 0..63
        int dcol = df * 16 + (lane & 15);
        int byte = row * 256 + ((dcol * 2) ^ ((row & 15) << 4));
        *(unsigned short*)(kb + byte) = f2h(acc[df][r]);
      }
  }
  __syncthreads();

  STAGE_WT(Wv);
  __syncthreads();
#pragma unroll
  for (int df = 0; df < 8; ++df) acc[df] = (f32x4)(0.0f);
#pragma unroll
  for (int ks = 0; ks < 4; ++ks)
#pragma unroll
    for (int df = 0; df < 8; ++df) {
      f16x8 bf = lds_read8w(wt, df * 16 + (lane & 15), (lane >> 4) * 16 + ks * 64);
      acc[df] = __builtin_amdgcn_mfma_f32_16x16x32_f16(ah[ks], bf, acc[df], 0, 0, 0);
    }
  {
    unsigned char* vb = (unsigned char*)vt_ws + ((size_t)b * NTILES + kt) * 16384;
#pragma unroll
    for (int df = 0; df < 8; ++df)
#pragma unroll
      for (int r = 0; r < 4; ++r) {
        int row = wv * 16 + (lane >> 4) * 4 + r;   // tile-local m
        int dcol = df * 16 + (lane & 15);          // d (row of V^T tile)
        int byte = dcol * 128 + ((row * 2) ^ ((dcol & 7) << 4));
        *(unsigned short*)(vb + byte) = f2h(acc[df][r]);
      }
  }
#undef STAGE_WT
}

// ---------------------------------------------------------------------------
// Kernel B: flash attention, 32x32 MFMA, in-register P.
// grid 512 x 256 thr (4 waves x 32 q-rows). LDS 64KB:
//  prologue: xa/q [128][256B] @0 (32K), wq^T @32K (32K)
//  main: K[2] @0/16K ([64 kv][256B] swz4), V[2] @32K/48K ([128 d][128B] swz3)
//  epilogue: O bounce [128 q][512B] @0 (64K)
// ---------------------------------------------------------------------------
__global__ __launch_bounds__(256, 2) void attn_kernel(
    const float* __restrict__ x, const float* __restrict__ Wq,
    const unsigned short* __restrict__ k_ws,
    const unsigned short* __restrict__ vt_ws, float* __restrict__ out) {
  __shared__ unsigned char smem[64 * 1024];

  const int bx = blockIdx.x;
  const int wb = ((bx & 7) << 6) | (bx >> 3);  // XCD swizzle (512 % 8 == 0)
  const int b = wb >> 7;
  const int t_ = (wb >> 4) & 7;
  const int n0 = (wb & 15) * QROWS;
  const int tid = threadIdx.x;
  const int wv = tid >> 6, lane = tid & 63;
  const int c = lane & 15, g = lane >> 4;
  const int l31 = lane & 31, hi = lane >> 5;

  const float* xg = x + (((size_t)b * Tn + t_) * Nn + n0) * Cn;  // 128x128
  unsigned char* xa = smem;
  unsigned char* wqb = smem + 32 * 1024;

  // ---- prologue: q = x@Wq (f16) * log2e (16x16 path, as R9) ----
  const float LOG2E = 1.4426950408889634f;
  {
    const float4* gp = (const float4*)xg;
#pragma unroll
    for (int ii = 0; ii < 16; ++ii) {
      int f = tid + ii * 256;
      int row = f >> 5, c4 = f & 31;
      float4 v = gp[f];
      int byte = row * 256 + ((c4 * 8) ^ ((row & 15) << 4));
      *(ushort4*)(xa + byte) =
          make_ushort4(f2h(v.x), f2h(v.y), f2h(v.z), f2h(v.w));
    }
  }
  {
    const float4* gp = (const float4*)Wq;
#pragma unroll
    for (int ii = 0; ii < 16; ++ii) {
      int f = tid + ii * 256;
      int cc = f >> 5, d0 = (f & 31) * 4;
      float4 v = gp[f];
      float vv[4] = {v.x, v.y, v.z, v.w};
#pragma unroll
      for (int j = 0; j < 4; ++j) {
        int row = d0 + j;
        int byte = row * 256 + ((cc * 2) ^ ((row & 15) << 4));
        *(unsigned short*)(wqb + byte) = f2h(vv[j] * LOG2E);
      }
    }
  }
  __syncthreads();

  {
    f32x4 qacc[2][8];
#pragma unroll
    for (int rb = 0; rb < 2; ++rb)
#pragma unroll
      for (int df = 0; df < 8; ++df) qacc[rb][df] = (f32x4)(0.0f);
    f16x8 xf[2][4];
#pragma unroll
    for (int rb = 0; rb < 2; ++rb)
#pragma unroll
      for (int ks = 0; ks < 4; ++ks)
        xf[rb][ks] = lds_read8w(xa, wv * 32 + rb * 16 + c, g * 16 + ks * 64);
#pragma unroll
    for (int ks = 0; ks < 4; ++ks)
#pragma unroll
      for (int df = 0; df < 8; ++df) {
        f16x8 bf = lds_read8w(wqb, df * 16 + c, g * 16 + ks * 64);
        qacc[0][df] = __builtin_amdgcn_mfma_f32_16x16x32_f16(xf[0][ks], bf, qacc[0][df], 0, 0, 0);
        qacc[1][df] = __builtin_amdgcn_mfma_f32_16x16x32_f16(xf[1][ks], bf, qacc[1][df], 0, 0, 0);
      }
    // write q (f16) into own rows of xa (wave-local; in-wave ordering)
#pragma unroll
    for (int rb = 0; rb < 2; ++rb)
#pragma unroll
      for (int df = 0; df < 8; ++df)
#pragma unroll
        for (int r = 0; r < 4; ++r) {
          int row = wv * 32 + rb * 16 + g * 4 + r;
          int col = df * 16 + c;
          int byte = row * 256 + ((col * 2) ^ ((row & 15) << 4));
          *(unsigned short*)(xa + byte) = f2h(qacc[rb][df][r]);
        }
  }
  // read q as 32x32 B-frags: lane holds col q=l31, rows d = kc*16+hi*8..+7
  f16x8 qf[8];
#pragma unroll
  for (int kc = 0; kc < 8; ++kc)
    qf[kc] = lds_read8w(xa, wv * 32 + l31, kc * 32 + hi * 16);
  __syncthreads();  // xa/wqb dead; K/V staging takes over

  // ---- main flash loop ----
  f32x16 o[4];
#pragma unroll
  for (int dblk = 0; dblk < 4; ++dblk) o[dblk] = (f32x16)(0.0f);
  float mrow = -INFINITY;
  float lrow = 0.f;  // per-lane partial (hi halves merged at end)

  const unsigned char* khg = (const unsigned char*)k_ws + (size_t)b * NTILES * 16384;
  const unsigned char* vtg = (const unsigned char*)vt_ws + (size_t)b * NTILES * 16384;

  auto stage = [&](int t) {
    unsigned char* kd = smem + (t & 1) * 16384 + tid * 16;
    unsigned char* vd = smem + 32 * 1024 + (t & 1) * 16384 + tid * 16;
    const unsigned char* ksrc = khg + (size_t)t * 16384 + tid * 16;
    const unsigned char* vsrc = vtg + (size_t)t * 16384 + tid * 16;
#pragma unroll
    for (int h = 0; h < 4; ++h) {
      gld16(ksrc + h * 4096, kd + h * 4096);
      gld16(vsrc + h * 4096, vd + h * 4096);
    }
  };

  stage(0);
  __syncthreads();

#pragma unroll 1
  for (int t = 0; t < NTILES; ++t) {
    unsigned char* kb = smem + (t & 1) * 16384;
    unsigned char* vb = smem + 32 * 1024 + (t & 1) * 16384;
    if (t + 1 < NTILES) stage(t + 1);

    // QK^T: S^T[64 kv][32 q], two 32x32 tiles. A=K rows kv, B=Q cols q.
    f32x16 s0 = (f32x16)(0.0f), s1 = (f32x16)(0.0f);
    __builtin_amdgcn_s_setprio(1);
#pragma unroll
    for (int kc = 0; kc < 8; ++kc) {
      f16x8 kf0 = lds_read8w(kb, l31, kc * 32 + hi * 16);
      f16x8 kf1 = lds_read8w(kb, 32 + l31, kc * 32 + hi * 16);
      s0 = __builtin_amdgcn_mfma_f32_32x32x16_f16(kf0, qf[kc], s0, 0, 0, 0);
      s1 = __builtin_amdgcn_mfma_f32_32x32x16_f16(kf1, qf[kc], s1, 0, 0, 0);
    }
    __builtin_amdgcn_s_setprio(0);

    // softmax (log2 units): lane owns q-row l31 (kv split across hi halves)
    float tm;
    {
      float mx[16];
#pragma unroll
      for (int r = 0; r < 16; ++r) mx[r] = fmaxf(s0[r], s1[r]);
#pragma unroll
      for (int r = 0; r < 8; ++r) mx[r] = fmaxf(mx[r], mx[r + 8]);
#pragma unroll
      for (int r = 0; r < 4; ++r) mx[r] = fmaxf(mx[r], mx[r + 4]);
      tm = fmaxf(fmaxf(mx[0], mx[1]), fmaxf(mx[2], mx[3]));
    }
    tm = fmaxf(tm, __shfl_xor(tm, 32));
    if (__any(tm > mrow + 8.f)) {  // rare rescale path
      float newm = fmaxf(mrow, tm);
      float scl = exp2f(mrow - newm);
#pragma unroll
      for (int dblk = 0; dblk < 4; ++dblk) o[dblk] *= scl;
      lrow *= scl;
      mrow = newm;
    }
    {
      float ps = 0.f;
#pragma unroll
      for (int r = 0; r < 16; ++r) {
        float p = exp2f(s0[r] - mrow);
        s0[r] = p;
        ps += p;
      }
#pragma unroll
      for (int r = 0; r < 16; ++r) {
        float p = exp2f(s1[r] - mrow);
        s1[r] = p;
        ps += p;
      }
      lrow += ps;
    }

    // P -> 4 B-frags (16 kv each) entirely in registers
    f16x8 pf0, pf1, pf2, pf3;
    MKPF(pf0, s0, 0);
    MKPF(pf1, s0, 8);
    MKPF(pf2, s1, 0);
    MKPF(pf3, s1, 8);

    // PV: O^T[128 d][32 q] += V^T @ P. A=V^T rows d, B=P cols q.
    __builtin_amdgcn_s_setprio(1);
#pragma unroll
    for (int dblk = 0; dblk < 4; ++dblk) {
      f16x8 vf0 = lds_read8v(vb, dblk * 32 + l31, 0 * 32 + hi * 16);
      f16x8 vf1 = lds_read8v(vb, dblk * 32 + l31, 1 * 32 + hi * 16);
      f16x8 vf2 = lds_read8v(vb, dblk * 32 + l31, 2 * 32 + hi * 16);
      f16x8 vf3 = lds_read8v(vb, dblk * 32 + l31, 3 * 32 + hi * 16);
      o[dblk] = __builtin_amdgcn_mfma_f32_32x32x16_f16(vf0, pf0, o[dblk], 0, 0, 0);
      o[dblk] = __builtin_amdgcn_mfma_f32_32x32x16_f16(vf1, pf1, o[dblk], 0, 0, 0);
      o[dblk] = __builtin_amdgcn_mfma_f32_32x32x16_f16(vf2, pf2, o[dblk], 0, 0, 0);
      o[dblk] = __builtin_amdgcn_mfma_f32_32x32x16_f16(vf3, pf3, o[dblk], 0, 0, 0);
    }
    __builtin_amdgcn_s_setprio(0);
    __syncthreads();
  }

  // ---- epilogue: merge hi halves of l, bounce O via LDS, out = x + O/l ----
  lrow += __shfl_xor(lrow, 32);
  float inv = 1.0f / lrow;
  // write O/l (f32) to bounce [128 q][512B], swz (q&7)<<4
#pragma unroll
  for (int dblk = 0; dblk < 4; ++dblk)
#pragma unroll
    for (int rg = 0; rg < 4; ++rg) {
      f32x4 v;
      v[0] = o[dblk][rg * 4 + 0] * inv;
      v[1] = o[dblk][rg * 4 + 1] * inv;
      v[2] = o[dblk][rg * 4 + 2] * inv;
      v[3] = o[dblk][rg * 4 + 3] * inv;
      int row = wv * 32 + l31;
      int colb = dblk * 128 + rg * 32 + hi * 16;
      int byte = row * 512 + (colb ^ ((row & 7) << 4));
      *(f32x4*)(smem + byte) = v;
    }
  __syncthreads();
  {
    const float4* xg4 = (const float4*)xg;
    float4* og4 = (float4*)(out + (((size_t)b * Tn + t_) * Nn + n0) * Cn);
#pragma unroll
    for (int ii = 0; ii < 16; ++ii) {
      int f = tid + ii * 256;
      int row = f >> 5, slot = f & 31;
      int byte = row * 512 + ((slot * 16) ^ ((row & 7) << 4));
      f32x4 v = *(const f32x4*)(smem + byte);
      float4 xv = xg4[f];
      og4[f] = make_float4(xv.x + v[0], xv.y + v[1], xv.z + v[2], xv.w + v[3]);
    }
  }
}

extern "C" void kernel_launch(void* const* d_in, const int* in_sizes, int n_in,
                              void* d_out, int out_size, void* d_ws,
                              size_t ws_size, hipStream_t stream) {
  const float* x = (const float*)d_in[0];
  const float* rs = (const float*)d_in[1];
  const float* Wq = (const float*)d_in[2];
  const float* Wk = (const float*)d_in[3];
  const float* Wv = (const float*)d_in[4];
  float* out = (float*)d_out;

  // ws: K f16 tiles [B][32][16KB] (2MB) | V^T tiles [B][32][16KB] (2MB)
  unsigned short* k_ws = (unsigned short*)d_ws;
  unsigned short* vt_ws = k_ws + (size_t)Bn * Mn * Cn;

  proj_kv_kernel<<<Bn * NTILES, 256, 0, stream>>>(rs, Wk, Wv, k_ws, vt_ws);
  attn_kernel<<<Bn * Tn * NQT, 256, 0, stream>>>(x, Wq, k_ws, vt_ws, out);
}

// Round 12
// 121.683 us; speedup vs baseline: 1.3330x; 1.0017x over previous
//
#include <hip/hip_runtime.h>

// out = x + softmax((x@Wq) @ (rs@Wk)^T) @ (rs@Wv)
// B=4 T=8 N=2048 C=D=128 M=2048. fp32 in/out, fp16 MFMA compute (f32 accum).
// R10: 32x32x16 MFMA, swapped operands; S/P fully in registers (lane owns one
//      q-row); P->B-frags via cvt_pkrtz + v_permlane32_swap (no P LDS);
//      softmax = reg tree + 1 shuffle. LDS 64K = K[2]+V[2] only.

#define Bn 4
#define Tn 8
#define Nn 2048
#define Cn 128
#define Mn 2048
#define NTILES 32        // Mn/64
#define QROWS 128
#define NQT (Nn / QROWS) // 16

typedef __attribute__((ext_vector_type(4))) float f32x4;
typedef __attribute__((ext_vector_type(16))) float f32x16;
typedef __attribute__((ext_vector_type(8))) _Float16 f16x8;
typedef __attribute__((ext_vector_type(4))) unsigned int u32x4;
typedef __attribute__((address_space(3))) unsigned char lds_uc;
typedef const __attribute__((address_space(1))) unsigned char glb_uc;

__device__ __forceinline__ unsigned short f2h(float f) {
  _Float16 h = (_Float16)f;
  return __builtin_bit_cast(unsigned short, h);
}
__device__ __forceinline__ unsigned int pk2(float a, float b) {
  auto v = __builtin_amdgcn_cvt_pkrtz(a, b);
  return __builtin_bit_cast(unsigned int, v);
}
// 16B LDS read, 256B rows, swizzle (row&15)<<4
__device__ __forceinline__ f16x8 lds_read8w(const unsigned char* base, int row,
                                            int colByte) {
  int byte = row * 256 + (colByte ^ ((row & 15) << 4));
  return *(const f16x8*)(base + byte);
}
// 16B LDS read, 128B rows, swizzle (row&7)<<4
__device__ __forceinline__ f16x8 lds_read8v(const unsigned char* base, int row,
                                            int colByte) {
  int byte = row * 128 + (colByte ^ ((row & 7) << 4));
  return *(const f16x8*)(base + byte);
}
__device__ __forceinline__ void gld16(const void* g, void* l) {
  __builtin_amdgcn_global_load_lds((glb_uc*)g, (lds_uc*)l, 16, 0, 0);
}

// Build one PV B-frag (16 kv rows) from 8 P values in s[base..base+7].
// VGPR0=r0 of swap(pk(p0,p1),pk(p4,p5)); VGPR2=r1; VGPR1/3 from (p2,p3,p6,p7).
#define MKPF(dst, sv, base)                                        \
  {                                                                \
    unsigned a0 = pk2(sv[base + 0], sv[base + 1]);                 \
    unsigned b0 = pk2(sv[base + 4], sv[base + 5]);                 \
    unsigned a1 = pk2(sv[base + 2], sv[base + 3]);                 \
    unsigned b1 = pk2(sv[base + 6], sv[base + 7]);                 \
    asm("v_permlane32_swap_b32 %0, %1" : "+v"(a0), "+v"(b0));      \
    asm("v_permlane32_swap_b32 %0, %1" : "+v"(a1), "+v"(b1));      \
    u32x4 tmp = {a0, a1, b0, b1};                                  \
    dst = __builtin_bit_cast(f16x8, tmp);                          \
  }

// ---------------------------------------------------------------------------
// Kernel A: per (b,kt): K tile [64 kv][128 d] f16, 256B rows, swz (kv&15)<<4;
// V^T tile [128 d][64 m] f16, 128B rows, swz (d&7)<<4. Tiles 16KB each.
// grid: B*32 = 128 blocks, 256 threads. LDS 48KB.
// ---------------------------------------------------------------------------
__global__ __launch_bounds__(256) void proj_kv_kernel(
    const float* __restrict__ rs, const float* __restrict__ Wk,
    const float* __restrict__ Wv, unsigned short* __restrict__ k_ws,
    unsigned short* __restrict__ vt_ws) {
  __shared__ unsigned char smem[48 * 1024];
  unsigned char* rsh = smem;             // [64][128] f16 swz (16KB)
  unsigned char* wt = smem + 16 * 1024;  // [128][128] f16 swz, W^T (32KB)

  const int bid = blockIdx.x;
  const int b = bid >> 5;
  const int kt = bid & 31;
  const int m0 = kt << 6;
  const int tid = threadIdx.x;
  const int wv = tid >> 6, lane = tid & 63;

  {
    const float4* g = (const float4*)(rs + ((size_t)b * Mn + m0) * Cn);
#pragma unroll
    for (int i = 0; i < 8; ++i) {
      int f = tid + i * 256;
      int row = f >> 5, c4 = f & 31;
      float4 v = g[f];
      int byte = row * 256 + ((c4 * 8) ^ ((row & 15) << 4));
      *(ushort4*)(rsh + byte) =
          make_ushort4(f2h(v.x), f2h(v.y), f2h(v.z), f2h(v.w));
    }
  }

#define STAGE_WT(Wp)                                                          \
  {                                                                           \
    const float4* g = (const float4*)(Wp);                                    \
    _Pragma("unroll") for (int i = 0; i < 16; ++i) {                          \
      int f = tid + i * 256;                                                  \
      int cc = f >> 5, d0 = (f & 31) * 4;                                     \
      float4 v = g[f];                                                        \
      float vv[4] = {v.x, v.y, v.z, v.w};                                     \
      _Pragma("unroll") for (int j = 0; j < 4; ++j) {                         \
        int row = d0 + j;                                                     \
        int byte = row * 256 + ((cc * 2) ^ ((row & 15) << 4));                \
        *(unsigned short*)(wt + byte) = f2h(vv[j]);                           \
      }                                                                       \
    }                                                                         \
  }

  STAGE_WT(Wk);
  __syncthreads();

  const int arow = wv * 16 + (lane & 15);
  f16x8 ah[4];
#pragma unroll
  for (int ks = 0; ks < 4; ++ks)
    ah[ks] = lds_read8w(rsh, arow, (lane >> 4) * 16 + ks * 64);

  f32x4 acc[8];
#pragma unroll
  for (int df = 0; df < 8; ++df) acc[df] = (f32x4)(0.0f);
#pragma unroll
  for (int ks = 0; ks < 4; ++ks)
#pragma unroll
    for (int df = 0; df < 8; ++df) {
      f16x8 bf = lds_read8w(wt, df * 16 + (lane & 15), (lane >> 4) * 16 + ks * 64);
      acc[df] = __builtin_amdgcn_mfma_f32_16x16x32_f16(ah[ks], bf, acc[df], 0, 0, 0);
    }
  {
    unsigned char* kb = (unsigned char*)k_ws + ((size_t)b * NTILES + kt) * 16384;
#pragma unroll
    for (int df = 0; df < 8; ++df)
#pragma unroll
      for (int r = 0; r < 4; ++r) {
        int row = wv * 16 + (lane >> 4) * 4 + r;   // tile-local kv 0..63
        int dcol = df * 16 + (lane & 15);
        int byte = row * 256 + ((dcol * 2) ^ ((row & 15) << 4));
        *(unsigned short*)(kb + byte) = f2h(acc[df][r]);
      }
  }
  __syncthreads();

  STAGE_WT(Wv);
  __syncthreads();
#pragma unroll
  for (int df = 0; df < 8; ++df) acc[df] = (f32x4)(0.0f);
#pragma unroll
  for (int ks = 0; ks < 4; ++ks)
#pragma unroll
    for (int df = 0; df < 8; ++df) {
      f16x8 bf = lds_read8w(wt, df * 16 + (lane & 15), (lane >> 4) * 16 + ks * 64);
      acc[df] = __builtin_amdgcn_mfma_f32_16x16x32_f16(ah[ks], bf, acc[df], 0, 0, 0);
    }
  {
    unsigned char* vb = (unsigned char*)vt_ws + ((size_t)b * NTILES + kt) * 16384;
#pragma unroll
    for (int df = 0; df < 8; ++df)
#pragma unroll
      for (int r = 0; r < 4; ++r) {
        int row = wv * 16 + (lane >> 4) * 4 + r;   // tile-local m
        int dcol = df * 16 + (lane & 15);          // d (row of V^T tile)
        int byte = dcol * 128 + ((row * 2) ^ ((dcol & 7) << 4));
        *(unsigned short*)(vb + byte) = f2h(acc[df][r]);
      }
  }
#undef STAGE_WT
}

// ---------------------------------------------------------------------------
// Kernel B: flash attention, 32x32 MFMA, in-register P.
// grid 512 x 256 thr (4 waves x 32 q-rows). LDS 64KB:
//  prologue: xa/q [128][256B] @0 (32K), wq^T @32K (32K)
//  main: K[2] @0/16K ([64 kv][256B] swz4), V[2] @32K/48K ([128 d][128B] swz3)
//  epilogue: O bounce [128 q][512B] @0 (64K)
// ---------------------------------------------------------------------------
__global__ __launch_bounds__(256, 2) void attn_kernel(
    const float* __restrict__ x, const float* __restrict__ Wq,
    const unsigned short* __restrict__ k_ws,
    const unsigned short* __restrict__ vt_ws, float* __restrict__ out) {
  __shared__ unsigned char smem[64 * 1024];

  const int bx = blockIdx.x;
  const int wb = ((bx & 7) << 6) | (bx >> 3);  // XCD swizzle (512 % 8 == 0)
  const int b = wb >> 7;
  const int t_ = (wb >> 4) & 7;
  const int n0 = (wb & 15) * QROWS;
  const int tid = threadIdx.x;
  const int wv = tid >> 6, lane = tid & 63;
  const int c = lane & 15, g = lane >> 4;
  const int l31 = lane & 31, hi = lane >> 5;

  const float* xg = x + (((size_t)b * Tn + t_) * Nn + n0) * Cn;  // 128x128
  unsigned char* xa = smem;
  unsigned char* wqb = smem + 32 * 1024;

  // ---- prologue: q = x@Wq (f16) * log2e (16x16 path, as R9) ----
  const float LOG2E = 1.4426950408889634f;
  {
    const float4* gp = (const float4*)xg;
#pragma unroll
    for (int ii = 0; ii < 16; ++ii) {
      int f = tid + ii * 256;
      int row = f >> 5, c4 = f & 31;
      float4 v = gp[f];
      int byte = row * 256 + ((c4 * 8) ^ ((row & 15) << 4));
      *(ushort4*)(xa + byte) =
          make_ushort4(f2h(v.x), f2h(v.y), f2h(v.z), f2h(v.w));
    }
  }
  {
    const float4* gp = (const float4*)Wq;
#pragma unroll
    for (int ii = 0; ii < 16; ++ii) {
      int f = tid + ii * 256;
      int cc = f >> 5, d0 = (f & 31) * 4;
      float4 v = gp[f];
      float vv[4] = {v.x, v.y, v.z, v.w};
#pragma unroll
      for (int j = 0; j < 4; ++j) {
        int row = d0 + j;
        int byte = row * 256 + ((cc * 2) ^ ((row & 15) << 4));
        *(unsigned short*)(wqb + byte) = f2h(vv[j] * LOG2E);
      }
    }
  }
  __syncthreads();

  {
    f32x4 qacc[2][8];
#pragma unroll
    for (int rb = 0; rb < 2; ++rb)
#pragma unroll
      for (int df = 0; df < 8; ++df) qacc[rb][df] = (f32x4)(0.0f);
    f16x8 xf[2][4];
#pragma unroll
    for (int rb = 0; rb < 2; ++rb)
#pragma unroll
      for (int ks = 0; ks < 4; ++ks)
        xf[rb][ks] = lds_read8w(xa, wv * 32 + rb * 16 + c, g * 16 + ks * 64);
#pragma unroll
    for (int ks = 0; ks < 4; ++ks)
#pragma unroll
      for (int df = 0; df < 8; ++df) {
        f16x8 bf = lds_read8w(wqb, df * 16 + c, g * 16 + ks * 64);
        qacc[0][df] = __builtin_amdgcn_mfma_f32_16x16x32_f16(xf[0][ks], bf, qacc[0][df], 0, 0, 0);
        qacc[1][df] = __builtin_amdgcn_mfma_f32_16x16x32_f16(xf[1][ks], bf, qacc[1][df], 0, 0, 0);
      }
    // write q (f16) into own rows of xa (wave-local; in-wave ordering)
#pragma unroll
    for (int rb = 0; rb < 2; ++rb)
#pragma unroll
      for (int df = 0; df < 8; ++df)
#pragma unroll
        for (int r = 0; r < 4; ++r) {
          int row = wv * 32 + rb * 16 + g * 4 + r;
          int col = df * 16 + c;
          int byte = row * 256 + ((col * 2) ^ ((row & 15) << 4));
          *(unsigned short*)(xa + byte) = f2h(qacc[rb][df][r]);
        }
  }
  // read q as 32x32 B-frags: lane holds col q=l31, rows d = kc*16+hi*8..+7
  f16x8 qf[8];
#pragma unroll
  for (int kc = 0; kc < 8; ++kc)
    qf[kc] = lds_read8w(xa, wv * 32 + l31, kc * 32 + hi * 16);
  __syncthreads();  // xa/wqb dead; K/V staging takes over

  // ---- main flash loop ----
  f32x16 o[4];
#pragma unroll
  for (int dblk = 0; dblk < 4; ++dblk) o[dblk] = (f32x16)(0.0f);
  float mrow = -INFINITY;
  float lrow = 0.f;  // per-lane partial (hi halves merged at end)

  const unsigned char* khg = (const unsigned char*)k_ws + (size_t)b * NTILES * 16384;
  const unsigned char* vtg = (const unsigned char*)vt_ws + (size_t)b * NTILES * 16384;

  auto stage = [&](int t) {
    unsigned char* kd = smem + (t & 1) * 16384 + tid * 16;
    unsigned char* vd = smem + 32 * 1024 + (t & 1) * 16384 + tid * 16;
    const unsigned char* ksrc = khg + (size_t)t * 16384 + tid * 16;
    const unsigned char* vsrc = vtg + (size_t)t * 16384 + tid * 16;
#pragma unroll
    for (int h = 0; h < 4; ++h) {
      gld16(ksrc + h * 4096, kd + h * 4096);
      gld16(vsrc + h * 4096, vd + h * 4096);
    }
  };

  stage(0);
  __syncthreads();

#pragma unroll 1
  for (int t = 0; t < NTILES; ++t) {
    unsigned char* kb = smem + (t & 1) * 16384;
    unsigned char* vb = smem + 32 * 1024 + (t & 1) * 16384;
    if (t + 1 < NTILES) stage(t + 1);

    // QK^T: S^T[64 kv][32 q], two 32x32 tiles. A=K rows kv, B=Q cols q.
    f32x16 s0 = (f32x16)(0.0f), s1 = (f32x16)(0.0f);
    __builtin_amdgcn_s_setprio(1);
#pragma unroll
    for (int kc = 0; kc < 8; ++kc) {
      f16x8 kf0 = lds_read8w(kb, l31, kc * 32 + hi * 16);
      f16x8 kf1 = lds_read8w(kb, 32 + l31, kc * 32 + hi * 16);
      s0 = __builtin_amdgcn_mfma_f32_32x32x16_f16(kf0, qf[kc], s0, 0, 0, 0);
      s1 = __builtin_amdgcn_mfma_f32_32x32x16_f16(kf1, qf[kc], s1, 0, 0, 0);
    }
    __builtin_amdgcn_s_setprio(0);

    // softmax (log2 units): lane owns q-row l31 (kv split across hi halves)
    float tm;
    {
      float mx[16];
#pragma unroll
      for (int r = 0; r < 16; ++r) mx[r] = fmaxf(s0[r], s1[r]);
#pragma unroll
      for (int r = 0; r < 8; ++r) mx[r] = fmaxf(mx[r], mx[r + 8]);
#pragma unroll
      for (int r = 0; r < 4; ++r) mx[r] = fmaxf(mx[r], mx[r + 4]);
      tm = fmaxf(fmaxf(mx[0], mx[1]), fmaxf(mx[2], mx[3]));
    }
    tm = fmaxf(tm, __shfl_xor(tm, 32));
    if (__any(tm > mrow + 8.f)) {  // rare rescale path
      float newm = fmaxf(mrow, tm);
      float scl = exp2f(mrow - newm);
#pragma unroll
      for (int dblk = 0; dblk < 4; ++dblk) o[dblk] *= scl;
      lrow *= scl;
      mrow = newm;
    }
    {
      float ps = 0.f;
#pragma unroll
      for (int r = 0; r < 16; ++r) {
        float p = exp2f(s0[r] - mrow);
        s0[r] = p;
        ps += p;
      }
#pragma unroll
      for (int r = 0; r < 16; ++r) {
        float p = exp2f(s1[r] - mrow);
        s1[r] = p;
        ps += p;
      }
      lrow += ps;
    }

    // P -> 4 B-frags (16 kv each) entirely in registers
    f16x8 pf0, pf1, pf2, pf3;
    MKPF(pf0, s0, 0);
    MKPF(pf1, s0, 8);
    MKPF(pf2, s1, 0);
    MKPF(pf3, s1, 8);

    // PV: O^T[128 d][32 q] += V^T @ P. A=V^T rows d, B=P cols q.
    __builtin_amdgcn_s_setprio(1);
#pragma unroll
    for (int dblk = 0; dblk < 4; ++dblk) {
      f16x8 vf0 = lds_read8v(vb, dblk * 32 + l31, 0 * 32 + hi * 16);
      f16x8 vf1 = lds_read8v(vb, dblk * 32 + l31, 1 * 32 + hi * 16);
      f16x8 vf2 = lds_read8v(vb, dblk * 32 + l31, 2 * 32 + hi * 16);
      f16x8 vf3 = lds_read8v(vb, dblk * 32 + l31, 3 * 32 + hi * 16);
      o[dblk] = __builtin_amdgcn_mfma_f32_32x32x16_f16(vf0, pf0, o[dblk], 0, 0, 0);
      o[dblk] = __builtin_amdgcn_mfma_f32_32x32x16_f16(vf1, pf1, o[dblk], 0, 0, 0);
      o[dblk] = __builtin_amdgcn_mfma_f32_32x32x16_f16(vf2, pf2, o[dblk], 0, 0, 0);
      o[dblk] = __builtin_amdgcn_mfma_f32_32x32x16_f16(vf3, pf3, o[dblk], 0, 0, 0);
    }
    __builtin_amdgcn_s_setprio(0);
    __syncthreads();
  }

  // ---- epilogue: merge hi halves of l, bounce O via LDS, out = x + O/l ----
  lrow += __shfl_xor(lrow, 32);
  float inv = 1.0f / lrow;
  // write O/l (f32) to bounce [128 q][512B], swz (q&7)<<4
#pragma unroll
  for (int dblk = 0; dblk < 4; ++dblk)
#pragma unroll
    for (int rg = 0; rg < 4; ++rg) {
      f32x4 v;
      v[0] = o[dblk][rg * 4 + 0] * inv;
      v[1] = o[dblk][rg * 4 + 1] * inv;
      v[2] = o[dblk][rg * 4 + 2] * inv;
      v[3] = o[dblk][rg * 4 + 3] * inv;
      int row = wv * 32 + l31;
      int colb = dblk * 128 + rg * 32 + hi * 16;
      int byte = row * 512 + (colb ^ ((row & 7) << 4));
      *(f32x4*)(smem + byte) = v;
    }
  __syncthreads();
  {
    const float4* xg4 = (const float4*)xg;
    float4* og4 = (float4*)(out + (((size_t)b * Tn + t_) * Nn + n0) * Cn);
#pragma unroll
    for (int ii = 0; ii < 16; ++ii) {
      int f = tid + ii * 256;
      int row = f >> 5, slot = f & 31;
      int byte = row * 512 + ((slot * 16) ^ ((row & 7) << 4));
      f32x4 v = *(const f32x4*)(smem + byte);
      float4 xv = xg4[f];
      og4[f] = make_float4(xv.x + v[0], xv.y + v[1], xv.z + v[2], xv.w + v[3]);
    }
  }
}

extern "C" void kernel_launch(void* const* d_in, const int* in_sizes, int n_in,
                              void* d_out, int out_size, void* d_ws,
                              size_t ws_size, hipStream_t stream) {
  const float* x = (const float*)d_in[0];
  const float* rs = (const float*)d_in[1];
  const float* Wq = (const float*)d_in[2];
  const float* Wk = (const float*)d_in[3];
  const float* Wv = (const float*)d_in[4];
  float* out = (float*)d_out;

  // ws: K f16 tiles [B][32][16KB] (2MB) | V^T tiles [B][32][16KB] (2MB)
  unsigned short* k_ws = (unsigned short*)d_ws;
  unsigned short* vt_ws = k_ws + (size_t)Bn * Mn * Cn;

  proj_kv_kernel<<<Bn * NTILES, 256, 0, stream>>>(rs, Wk, Wv, k_ws, vt_ws);
  attn_kernel<<<Bn * Tn * NQT, 256, 0, stream>>>(x, Wq, k_ws, vt_ws, out);
}

// Round 13
// 109.735 us; speedup vs baseline: 1.4782x; 1.1089x over previous
//
#include <hip/hip_runtime.h>

// out = x + softmax((x@Wq) @ (rs@Wk)^T) @ (rs@Wv)
// B=4 T=8 N=2048 C=D=128 M=2048. fp32 in/out, fp16 MFMA compute (f32 accum).
// R11 = R10 + intra-tile ping-pong: tile split into two 32-kv subtiles;
//       softmax(sub0) on VALU overlaps QK^T(sub1) MFMA; softmax(sub1)
//       overlaps PV(sub0). exp via __builtin_amdgcn_exp2f.

#define Bn 4
#define Tn 8
#define Nn 2048
#define Cn 128
#define Mn 2048
#define NTILES 32        // Mn/64
#define QROWS 128
#define NQT (Nn / QROWS) // 16

typedef __attribute__((ext_vector_type(4))) float f32x4;
typedef __attribute__((ext_vector_type(16))) float f32x16;
typedef __attribute__((ext_vector_type(8))) _Float16 f16x8;
typedef __attribute__((ext_vector_type(4))) unsigned int u32x4;
typedef __attribute__((address_space(3))) unsigned char lds_uc;
typedef const __attribute__((address_space(1))) unsigned char glb_uc;

__device__ __forceinline__ unsigned short f2h(float f) {
  _Float16 h = (_Float16)f;
  return __builtin_bit_cast(unsigned short, h);
}
__device__ __forceinline__ unsigned int pk2(float a, float b) {
  auto v = __builtin_amdgcn_cvt_pkrtz(a, b);
  return __builtin_bit_cast(unsigned int, v);
}
// 16B LDS read, 256B rows, swizzle (row&15)<<4
__device__ __forceinline__ f16x8 lds_read8w(const unsigned char* base, int row,
                                            int colByte) {
  int byte = row * 256 + (colByte ^ ((row & 15) << 4));
  return *(const f16x8*)(base + byte);
}
// 16B LDS read, 128B rows, swizzle (row&7)<<4
__device__ __forceinline__ f16x8 lds_read8v(const unsigned char* base, int row,
                                            int colByte) {
  int byte = row * 128 + (colByte ^ ((row & 7) << 4));
  return *(const f16x8*)(base + byte);
}
__device__ __forceinline__ void gld16(const void* g, void* l) {
  __builtin_amdgcn_global_load_lds((glb_uc*)g, (lds_uc*)l, 16, 0, 0);
}

// Build one PV B-frag (16 kv rows) from 8 P values in s[base..base+7].
// (mapping validated in R10: absmax matched fp16-precision expectation)
#define MKPF(dst, sv, base)                                        \
  {                                                                \
    unsigned a0 = pk2(sv[base + 0], sv[base + 1]);                 \
    unsigned b0 = pk2(sv[base + 4], sv[base + 5]);                 \
    unsigned a1 = pk2(sv[base + 2], sv[base + 3]);                 \
    unsigned b1 = pk2(sv[base + 6], sv[base + 7]);                 \
    asm("v_permlane32_swap_b32 %0, %1" : "+v"(a0), "+v"(b0));      \
    asm("v_permlane32_swap_b32 %0, %1" : "+v"(a1), "+v"(b1));      \
    u32x4 tmp = {a0, a1, b0, b1};                                  \
    dst = __builtin_bit_cast(f16x8, tmp);                          \
  }

// ---------------------------------------------------------------------------
// Kernel A: per (b,kt): K tile [64 kv][128 d] f16, 256B rows, swz (kv&15)<<4;
// V^T tile [128 d][64 m] f16, 128B rows, swz (d&7)<<4. Tiles 16KB each.
// grid: B*32 = 128 blocks, 256 threads. LDS 48KB.
// ---------------------------------------------------------------------------
__global__ __launch_bounds__(256) void proj_kv_kernel(
    const float* __restrict__ rs, const float* __restrict__ Wk,
    const float* __restrict__ Wv, unsigned short* __restrict__ k_ws,
    unsigned short* __restrict__ vt_ws) {
  __shared__ unsigned char smem[48 * 1024];
  unsigned char* rsh = smem;             // [64][128] f16 swz (16KB)
  unsigned char* wt = smem + 16 * 1024;  // [128][128] f16 swz, W^T (32KB)

  const int bid = blockIdx.x;
  const int b = bid >> 5;
  const int kt = bid & 31;
  const int m0 = kt << 6;
  const int tid = threadIdx.x;
  const int wv = tid >> 6, lane = tid & 63;

  {
    const float4* g = (const float4*)(rs + ((size_t)b * Mn + m0) * Cn);
#pragma unroll
    for (int i = 0; i < 8; ++i) {
      int f = tid + i * 256;
      int row = f >> 5, c4 = f & 31;
      float4 v = g[f];
      int byte = row * 256 + ((c4 * 8) ^ ((row & 15) << 4));
      *(ushort4*)(rsh + byte) =
          make_ushort4(f2h(v.x), f2h(v.y), f2h(v.z), f2h(v.w));
    }
  }

#define STAGE_WT(Wp)                                                          \
  {                                                                           \
    const float4* g = (const float4*)(Wp);                                    \
    _Pragma("unroll") for (int i = 0; i < 16; ++i) {                          \
      int f = tid + i * 256;                                                  \
      int cc = f >> 5, d0 = (f & 31) * 4;                                     \
      float4 v = g[f];                                                        \
      float vv[4] = {v.x, v.y, v.z, v.w};                                     \
      _Pragma("unroll") for (int j = 0; j < 4; ++j) {                         \
        int row = d0 + j;                                                     \
        int byte = row * 256 + ((cc * 2) ^ ((row & 15) << 4));                \
        *(unsigned short*)(wt + byte) = f2h(vv[j]);                           \
      }                                                                       \
    }                                                                         \
  }

  STAGE_WT(Wk);
  __syncthreads();

  const int arow = wv * 16 + (lane & 15);
  f16x8 ah[4];
#pragma unroll
  for (int ks = 0; ks < 4; ++ks)
    ah[ks] = lds_read8w(rsh, arow, (lane >> 4) * 16 + ks * 64);

  f32x4 acc[8];
#pragma unroll
  for (int df = 0; df < 8; ++df) acc[df] = (f32x4)(0.0f);
#pragma unroll
  for (int ks = 0; ks < 4; ++ks)
#pragma unroll
    for (int df = 0; df < 8; ++df) {
      f16x8 bf = lds_read8w(wt, df * 16 + (lane & 15), (lane >> 4) * 16 + ks * 64);
      acc[df] = __builtin_amdgcn_mfma_f32_16x16x32_f16(ah[ks], bf, acc[df], 0, 0, 0);
    }
  {
    unsigned char* kb = (unsigned char*)k_ws + ((size_t)b * NTILES + kt) * 16384;
#pragma unroll
    for (int df = 0; df < 8; ++df)
#pragma unroll
      for (int r = 0; r < 4; ++r) {
        int row = wv * 16 + (lane >> 4) * 4 + r;   // tile-local kv 0..63
        int dcol = df * 16 + (lane & 15);
        int byte = row * 256 + ((dcol * 2) ^ ((row & 15) << 4));
        *(unsigned short*)(kb + byte) = f2h(acc[df][r]);
      }
  }
  __syncthreads();

  STAGE_WT(Wv);
  __syncthreads();
#pragma unroll
  for (int df = 0; df < 8; ++df) acc[df] = (f32x4)(0.0f);
#pragma unroll
  for (int ks = 0; ks < 4; ++ks)
#pragma unroll
    for (int df = 0; df < 8; ++df) {
      f16x8 bf = lds_read8w(wt, df * 16 + (lane & 15), (lane >> 4) * 16 + ks * 64);
      acc[df] = __builtin_amdgcn_mfma_f32_16x16x32_f16(ah[ks], bf, acc[df], 0, 0, 0);
    }
  {
    unsigned char* vb = (unsigned char*)vt_ws + ((size_t)b * NTILES + kt) * 16384;
#pragma unroll
    for (int df = 0; df < 8; ++df)
#pragma unroll
      for (int r = 0; r < 4; ++r) {
        int row = wv * 16 + (lane >> 4) * 4 + r;   // tile-local m
        int dcol = df * 16 + (lane & 15);          // d (row of V^T tile)
        int byte = dcol * 128 + ((row * 2) ^ ((dcol & 7) << 4));
        *(unsigned short*)(vb + byte) = f2h(acc[df][r]);
      }
  }
#undef STAGE_WT
}

// ---------------------------------------------------------------------------
// Kernel B: flash attention, 32x32 MFMA, in-register P, subtile ping-pong.
// grid 512 x 256 thr (4 waves x 32 q-rows). LDS 64KB:
//  prologue: xa/q [128][256B] @0 (32K), wq^T @32K (32K)
//  main: K[2] @0/16K ([64 kv][256B] swz4), V[2] @32K/48K ([128 d][128B] swz3)
//  epilogue: O bounce [128 q][512B] @0 (64K)
// ---------------------------------------------------------------------------
__global__ __launch_bounds__(256, 2) void attn_kernel(
    const float* __restrict__ x, const float* __restrict__ Wq,
    const unsigned short* __restrict__ k_ws,
    const unsigned short* __restrict__ vt_ws, float* __restrict__ out) {
  __shared__ unsigned char smem[64 * 1024];

  const int bx = blockIdx.x;
  const int wb = ((bx & 7) << 6) | (bx >> 3);  // XCD swizzle (512 % 8 == 0)
  const int b = wb >> 7;
  const int t_ = (wb >> 4) & 7;
  const int n0 = (wb & 15) * QROWS;
  const int tid = threadIdx.x;
  const int wv = tid >> 6, lane = tid & 63;
  const int c = lane & 15, g = lane >> 4;
  const int l31 = lane & 31, hi = lane >> 5;

  const float* xg = x + (((size_t)b * Tn + t_) * Nn + n0) * Cn;  // 128x128
  unsigned char* xa = smem;
  unsigned char* wqb = smem + 32 * 1024;

  // ---- prologue: q = x@Wq (f16) * log2e (16x16 path) ----
  const float LOG2E = 1.4426950408889634f;
  {
    const float4* gp = (const float4*)xg;
#pragma unroll
    for (int ii = 0; ii < 16; ++ii) {
      int f = tid + ii * 256;
      int row = f >> 5, c4 = f & 31;
      float4 v = gp[f];
      int byte = row * 256 + ((c4 * 8) ^ ((row & 15) << 4));
      *(ushort4*)(xa + byte) =
          make_ushort4(f2h(v.x), f2h(v.y), f2h(v.z), f2h(v.w));
    }
  }
  {
    const float4* gp = (const float4*)Wq;
#pragma unroll
    for (int ii = 0; ii < 16; ++ii) {
      int f = tid + ii * 256;
      int cc = f >> 5, d0 = (f & 31) * 4;
      float4 v = gp[f];
      float vv[4] = {v.x, v.y, v.z, v.w};
#pragma unroll
      for (int j = 0; j < 4; ++j) {
        int row = d0 + j;
        int byte = row * 256 + ((cc * 2) ^ ((row & 15) << 4));
        *(unsigned short*)(wqb + byte) = f2h(vv[j] * LOG2E);
      }
    }
  }
  __syncthreads();

  {
    f32x4 qacc[2][8];
#pragma unroll
    for (int rb = 0; rb < 2; ++rb)
#pragma unroll
      for (int df = 0; df < 8; ++df) qacc[rb][df] = (f32x4)(0.0f);
    f16x8 xf[2][4];
#pragma unroll
    for (int rb = 0; rb < 2; ++rb)
#pragma unroll
      for (int ks = 0; ks < 4; ++ks)
        xf[rb][ks] = lds_read8w(xa, wv * 32 + rb * 16 + c, g * 16 + ks * 64);
#pragma unroll
    for (int ks = 0; ks < 4; ++ks)
#pragma unroll
      for (int df = 0; df < 8; ++df) {
        f16x8 bf = lds_read8w(wqb, df * 16 + c, g * 16 + ks * 64);
        qacc[0][df] = __builtin_amdgcn_mfma_f32_16x16x32_f16(xf[0][ks], bf, qacc[0][df], 0, 0, 0);
        qacc[1][df] = __builtin_amdgcn_mfma_f32_16x16x32_f16(xf[1][ks], bf, qacc[1][df], 0, 0, 0);
      }
    // write q (f16) into own rows of xa (wave-local; in-wave ordering)
#pragma unroll
    for (int rb = 0; rb < 2; ++rb)
#pragma unroll
      for (int df = 0; df < 8; ++df)
#pragma unroll
        for (int r = 0; r < 4; ++r) {
          int row = wv * 32 + rb * 16 + g * 4 + r;
          int col = df * 16 + c;
          int byte = row * 256 + ((col * 2) ^ ((row & 15) << 4));
          *(unsigned short*)(xa + byte) = f2h(qacc[rb][df][r]);
        }
  }
  // read q as 32x32 B-frags: lane holds col q=l31, rows d = kc*16+hi*8..+7
  f16x8 qf[8];
#pragma unroll
  for (int kc = 0; kc < 8; ++kc)
    qf[kc] = lds_read8w(xa, wv * 32 + l31, kc * 32 + hi * 16);
  __syncthreads();  // xa/wqb dead; K/V staging takes over

  // ---- main flash loop ----
  f32x16 o[4];
#pragma unroll
  for (int dblk = 0; dblk < 4; ++dblk) o[dblk] = (f32x16)(0.0f);
  float mrow = -INFINITY;
  float lrow = 0.f;  // per-lane partial (hi halves merged at end)

  const unsigned char* khg = (const unsigned char*)k_ws + (size_t)b * NTILES * 16384;
  const unsigned char* vtg = (const unsigned char*)vt_ws + (size_t)b * NTILES * 16384;

  auto stage = [&](int t) {
    unsigned char* kd = smem + (t & 1) * 16384 + tid * 16;
    unsigned char* vd = smem + 32 * 1024 + (t & 1) * 16384 + tid * 16;
    const unsigned char* ksrc = khg + (size_t)t * 16384 + tid * 16;
    const unsigned char* vsrc = vtg + (size_t)t * 16384 + tid * 16;
#pragma unroll
    for (int h = 0; h < 4; ++h) {
      gld16(ksrc + h * 4096, kd + h * 4096);
      gld16(vsrc + h * 4096, vd + h * 4096);
    }
  };

  // softmax for one 32-kv subtile held in s (16 regs + partner lane's 16)
  auto softmax_sub = [&](f32x16& s, f16x8& pfA, f16x8& pfB) {
    float mx[8];
#pragma unroll
    for (int r = 0; r < 8; ++r) mx[r] = fmaxf(s[r], s[r + 8]);
#pragma unroll
    for (int r = 0; r < 4; ++r) mx[r] = fmaxf(mx[r], mx[r + 4]);
    float tm = fmaxf(fmaxf(mx[0], mx[1]), fmaxf(mx[2], mx[3]));
    tm = fmaxf(tm, __shfl_xor(tm, 32));
    if (__any(tm > mrow + 8.f)) {  // rare rescale path
      float newm = fmaxf(mrow, tm);
      float scl = __builtin_amdgcn_exp2f(mrow - newm);
#pragma unroll
      for (int dblk = 0; dblk < 4; ++dblk) o[dblk] *= scl;
      lrow *= scl;
      mrow = newm;
    }
    float p[16];
#pragma unroll
    for (int r = 0; r < 16; ++r) p[r] = __builtin_amdgcn_exp2f(s[r] - mrow);
    float ps = 0.f;
    {
      float a[8];
#pragma unroll
      for (int r = 0; r < 8; ++r) a[r] = p[r] + p[r + 8];
#pragma unroll
      for (int r = 0; r < 4; ++r) a[r] += a[r + 4];
      ps = (a[0] + a[1]) + (a[2] + a[3]);
    }
    lrow += ps;
#pragma unroll
    for (int r = 0; r < 16; ++r) s[r] = p[r];
    MKPF(pfA, s, 0);
    MKPF(pfB, s, 8);
  };

  stage(0);
  __syncthreads();

#pragma unroll 1
  for (int t = 0; t < NTILES; ++t) {
    unsigned char* kb = smem + (t & 1) * 16384;
    unsigned char* vb = smem + 32 * 1024 + (t & 1) * 16384;

    // --- QK^T subtile 0 (kv 0..31): A=K rows l31 ---
    f32x16 s0 = (f32x16)(0.0f);
    __builtin_amdgcn_s_setprio(1);
#pragma unroll
    for (int kc = 0; kc < 8; ++kc) {
      f16x8 kf0 = lds_read8w(kb, l31, kc * 32 + hi * 16);
      s0 = __builtin_amdgcn_mfma_f32_32x32x16_f16(kf0, qf[kc], s0, 0, 0, 0);
    }
    __builtin_amdgcn_s_setprio(0);

    // start next-tile DMA early (addr VALU hides under s0 chain)
    if (t + 1 < NTILES) stage(t + 1);

    // --- QK^T subtile 1 (kv 32..63) issues; softmax0 overlaps on VALU ---
    f32x16 s1 = (f32x16)(0.0f);
    __builtin_amdgcn_s_setprio(1);
#pragma unroll
    for (int kc = 0; kc < 8; ++kc) {
      f16x8 kf1 = lds_read8w(kb, 32 + l31, kc * 32 + hi * 16);
      s1 = __builtin_amdgcn_mfma_f32_32x32x16_f16(kf1, qf[kc], s1, 0, 0, 0);
    }
    __builtin_amdgcn_s_setprio(0);

    f16x8 pf0, pf1;
    softmax_sub(s0, pf0, pf1);  // VALU, overlaps s1 MFMA latency

    // --- PV subtile 0 (kv 0..31 -> V cols 0..63B) ---
    __builtin_amdgcn_s_setprio(1);
#pragma unroll
    for (int dblk = 0; dblk < 4; ++dblk) {
      f16x8 vf0 = lds_read8v(vb, dblk * 32 + l31, 0 * 32 + hi * 16);
      f16x8 vf1 = lds_read8v(vb, dblk * 32 + l31, 1 * 32 + hi * 16);
      o[dblk] = __builtin_amdgcn_mfma_f32_32x32x16_f16(vf0, pf0, o[dblk], 0, 0, 0);
      o[dblk] = __builtin_amdgcn_mfma_f32_32x32x16_f16(vf1, pf1, o[dblk], 0, 0, 0);
    }
    __builtin_amdgcn_s_setprio(0);

    f16x8 pf2, pf3;
    softmax_sub(s1, pf2, pf3);  // VALU, overlaps PV0 MFMA

    // --- PV subtile 1 (kv 32..63 -> V cols 64..127B) ---
    __builtin_amdgcn_s_setprio(1);
#pragma unroll
    for (int dblk = 0; dblk < 4; ++dblk) {
      f16x8 vf2 = lds_read8v(vb, dblk * 32 + l31, 2 * 32 + hi * 16);
      f16x8 vf3 = lds_read8v(vb, dblk * 32 + l31, 3 * 32 + hi * 16);
      o[dblk] = __builtin_amdgcn_mfma_f32_32x32x16_f16(vf2, pf2, o[dblk], 0, 0, 0);
      o[dblk] = __builtin_amdgcn_mfma_f32_32x32x16_f16(vf3, pf3, o[dblk], 0, 0, 0);
    }
    __builtin_amdgcn_s_setprio(0);
    __syncthreads();
  }

  // ---- epilogue: merge hi halves of l, bounce O via LDS, out = x + O/l ----
  lrow += __shfl_xor(lrow, 32);
  float inv = 1.0f / lrow;
#pragma unroll
  for (int dblk = 0; dblk < 4; ++dblk)
#pragma unroll
    for (int rg = 0; rg < 4; ++rg) {
      f32x4 v;
      v[0] = o[dblk][rg * 4 + 0] * inv;
      v[1] = o[dblk][rg * 4 + 1] * inv;
      v[2] = o[dblk][rg * 4 + 2] * inv;
      v[3] = o[dblk][rg * 4 + 3] * inv;
      int row = wv * 32 + l31;
      int colb = dblk * 128 + rg * 32 + hi * 16;
      int byte = row * 512 + (colb ^ ((row & 7) << 4));
      *(f32x4*)(smem + byte) = v;
    }
  __syncthreads();
  {
    const float4* xg4 = (const float4*)xg;
    float4* og4 = (float4*)(out + (((size_t)b * Tn + t_) * Nn + n0) * Cn);
#pragma unroll
    for (int ii = 0; ii < 16; ++ii) {
      int f = tid + ii * 256;
      int row = f >> 5, slot = f & 31;
      int byte = row * 512 + ((slot * 16) ^ ((row & 7) << 4));
      f32x4 v = *(const f32x4*)(smem + byte);
      float4 xv = xg4[f];
      og4[f] = make_float4(xv.x + v[0], xv.y + v[1], xv.z + v[2], xv.w + v[3]);
    }
  }
}

extern "C" void kernel_launch(void* const* d_in, const int* in_sizes, int n_in,
                              void* d_out, int out_size, void* d_ws,
                              size_t ws_size, hipStream_t stream) {
  const float* x = (const float*)d_in[0];
  const float* rs = (const float*)d_in[1];
  const float* Wq = (const float*)d_in[2];
  const float* Wk = (const float*)d_in[3];
  const float* Wv = (const float*)d_in[4];
  float* out = (float*)d_out;

  // ws: K f16 tiles [B][32][16KB] (2MB) | V^T tiles [B][32][16KB] (2MB)
  unsigned short* k_ws = (unsigned short*)d_ws;
  unsigned short* vt_ws = k_ws + (size_t)Bn * Mn * Cn;

  proj_kv_kernel<<<Bn * NTILES, 256, 0, stream>>>(rs, Wk, Wv, k_ws, vt_ws);
  attn_kernel<<<Bn * Tn * NQT, 256, 0, stream>>>(x, Wq, k_ws, vt_ws, out);
}